// Round 6
// baseline (243.145 us; speedup 1.0000x reference)
//
#include <hip/hip_runtime.h>
#include <hip/hip_bf16.h>

// Problem constants (fixed by the reference setup)
#define N_ROWS   500000
#define NR1      25        // nr + 1
#define NGROUPS  20000     // N_ROWS / NR1
#define KCTX     20        // K context indices
#define H        128
#define NODES    10000
#define IDX_COLS 23        // 3 + K

typedef __attribute__((ext_vector_type(8))) short short8;   // 8 bf16 = 4 VGPRs
typedef __attribute__((ext_vector_type(4))) float f32x4;    // MFMA C/D

// pack two floats -> two bf16 (RNE) as a 32-bit word
__device__ __forceinline__ unsigned pkbf(float lo, float hi) {
  __hip_bfloat162 h = __float22bfloat162_rn(make_float2(lo, hi));
  union { __hip_bfloat162 h; unsigned u; } c; c.h = h;
  return c.u;
}
__device__ __forceinline__ float bf2f(unsigned short u) {
  union { unsigned u; float f; } c; c.u = ((unsigned)u) << 16; return c.f;
}

// ---------------------------------------------------------------------------
// Kernel A (v4): P[m] = x @ W1m.T via single-bf16 MFMA, P stored bf16.
// Error: bf16 W1+x rounding gives dP ~5e-4 rms; attenuated ~25x by W2*W3
// downstream (empirical R4->R5: P-level bf16 rounding left absmax unchanged).
// Grid (157, 3), block 256 = 4 waves; wave owns 16 nodes. LDS 34.8 KB.
// Block (0, m==2) additionally converts W2 -> bf16 w2b for k_main.
// ---------------------------------------------------------------------------
#define PN 64
__global__ __launch_bounds__(256) void k_precompute(
    const float* __restrict__ x, const float* __restrict__ W1,
    const float* __restrict__ W2,
    unsigned short* __restrict__ Pb, unsigned short* __restrict__ w2b) {
  __shared__ short wlds[128][136];   // bf16 W1m[j][k], padded: 34.8 KB

  const int tid   = threadIdx.x;
  const int m     = blockIdx.y;            // 0..2
  const int tbase = blockIdx.x * PN;       // node tile base

  // ---- stage W1m -> LDS bf16 (coalesced float4 reads) ----
#pragma unroll
  for (int it = 0; it < 16; ++it) {
    const int f  = it * 256 + tid;         // 0..4095 float4s (128 j x 32)
    const int j  = f >> 5;
    const int q4 = f & 31;
    const float4 v = *(const float4*)(W1 + (size_t)j * (3 * H) + m * H + q4 * 4);
    *(unsigned*)&wlds[j][q4 * 4]     = pkbf(v.x, v.y);
    *(unsigned*)&wlds[j][q4 * 4 + 2] = pkbf(v.z, v.w);
  }
  // ---- one block converts W2 -> bf16 global (needed by k_main) ----
  if (m == 2 && blockIdx.x == 0) {
    for (int i = tid; i < 64 * 64; i += 256) {
      const int n  = i >> 6;
      const int kp = i & 63;
      const float2 w = *(const float2*)(W2 + (size_t)n * H + kp * 2);
      *(unsigned*)&w2b[(size_t)n * H + kp * 2] = pkbf(w.x, w.y);
    }
  }
  __syncthreads();

  const int lane = tid & 63;
  const int wv   = tid >> 6;
  const int col  = lane & 15;
  const int quad = lane >> 4;

  int node = tbase + wv * 16 + col;
  if (node > NODES - 1) node = NODES - 1;
  const float4* __restrict__ xr = (const float4*)(x + (size_t)node * H);

  short8 Af[4];
#pragma unroll
  for (int kt = 0; kt < 4; ++kt) {
    const int f4 = kt * 8 + quad * 2;
    const float4 v0 = xr[f4], v1 = xr[f4 + 1];
    union { short8 v; unsigned u[4]; } pk;
    pk.u[0] = pkbf(v0.x, v0.y);
    pk.u[1] = pkbf(v0.z, v0.w);
    pk.u[2] = pkbf(v1.x, v1.y);
    pk.u[3] = pkbf(v1.z, v1.w);
    Af[kt] = pk.v;
  }

  f32x4 acc[8];
#pragma unroll
  for (int ct = 0; ct < 8; ++ct) acc[ct] = (f32x4)(0.f);

#pragma unroll
  for (int kt = 0; kt < 4; ++kt) {
#pragma unroll
    for (int ct = 0; ct < 8; ++ct) {
      const short8 Bf = *(const short8*)&wlds[ct * 16 + col][kt * 32 + quad * 8];
      acc[ct] = __builtin_amdgcn_mfma_f32_16x16x32_bf16(Af[kt], Bf, acc[ct], 0, 0, 0);
    }
  }

  // ---- write P[m] bf16; C row = quad*4+reg, col = ct*16 + (lane&15) ----
  unsigned short* __restrict__ Pm = Pb + (size_t)m * NODES * H;
#pragma unroll
  for (int reg = 0; reg < 4; ++reg) {
    const int n = tbase + wv * 16 + quad * 4 + reg;
    if (n < NODES) {
#pragma unroll
      for (int ct = 0; ct < 8; ++ct) {
        union { unsigned u; unsigned short s[2]; } c;
        c.u = pkbf(acc[ct][reg], 0.f);
        Pm[(size_t)n * H + ct * 16 + col] = c.s[0];
      }
    }
  }
}

// ---------------------------------------------------------------------------
// Kernel C (v5): fused main kernel.
//  - i0/i1 read directly from indices (k_pack deleted)
//  - P1/P2 gathers issued FIRST (raw bf16 short8 in regs), so their latency
//    hides behind the ctx-group phase
//  - B-fragments read directly from bf16 w2b global (16 KB, L1-resident)
//    -> no W2 staging phase, LDS = cgs only (3.7 KB)
// Block = 256 threads (4 waves), 128 rows; wave w owns rows [w*32, +32).
// ---------------------------------------------------------------------------
__global__ __launch_bounds__(256) void k_main(
    const int* __restrict__ indices,
    const unsigned short* __restrict__ P1b, const unsigned short* __restrict__ P2b,
    const unsigned short* __restrict__ P3b, const unsigned short* __restrict__ w2b,
    const float* __restrict__ b1, const float* __restrict__ b2,
    const float* __restrict__ W3, const float* __restrict__ b3,
    float* __restrict__ out) {
  __shared__ float cgs[7][132];    // context rows (b1 folded), padded: 3.7 KB

  const int tid   = threadIdx.x;
  const int rbase = blockIdx.x * 128;
  const int gbase = rbase / NR1;

  const int lane = tid & 63;
  const int wv   = tid >> 6;
  const int col  = lane & 15;
  const int quad = lane >> 4;
  const int Rw   = rbase + wv * 32;

  // ---- phase A: issue raw P1/P2 gathers up front ----
  int gl[2];
  short8 ua[2][4], ub[2][4];
#pragma unroll
  for (int rt = 0; rt < 2; ++rt) {
    const int r  = Rw + rt * 16 + col;
    const int rc = (r < N_ROWS) ? r : (N_ROWS - 1);
    const int i0 = indices[(size_t)rc * IDX_COLS + 0];
    const int i1 = indices[(size_t)rc * IDX_COLS + 1];
    const short8* __restrict__ pa = (const short8*)(P1b + (size_t)i0 * H);
    const short8* __restrict__ pb = (const short8*)(P2b + (size_t)i1 * H);
#pragma unroll
    for (int kt = 0; kt < 4; ++kt) {
      ua[rt][kt] = pa[kt * 4 + quad];
      ub[rt][kt] = pb[kt * 4 + quad];
    }
    gl[rt] = rc / NR1 - gbase;
  }

  // ---- phase B: context groups for this block (overlaps gather latency) ----
  {
    int rlast = rbase + 127; if (rlast > N_ROWS - 1) rlast = N_ROWS - 1;
    const int G   = rlast / NR1 - gbase + 1;   // <= 7
    const int j   = tid & 127;
    const int sub = tid >> 7;
#pragma unroll
    for (int it = 0; it < 4; ++it) {
      const int gi = it * 2 + sub;
      if (gi < G) {
        const int* __restrict__ rowidx =
            indices + (size_t)(gbase + gi) * NR1 * IDX_COLS + 3;
        float s = 0.f; int cnt = 0;
#pragma unroll
        for (int c = 0; c < KCTX; ++c) {
          const int idx = rowidx[c];
          s += bf2f(P3b[(size_t)idx * H + j]);
          cnt += (idx > 0) ? 1 : 0;
        }
        const float norm = (float)((cnt > 1) ? cnt : 1);
        cgs[gi][j] = b1[j] + s / norm;
      }
    }
  }
  __syncthreads();

  // ---- phase C: combine into A-fragments (bf16), MFMA layer 2 ----
  short8 A[2][4];
#pragma unroll
  for (int rt = 0; rt < 2; ++rt) {
#pragma unroll
    for (int kt = 0; kt < 4; ++kt) {
      union { short8 v; unsigned short s[8]; } va, vb;
      va.v = ua[rt][kt];
      vb.v = ub[rt][kt];
      const float4 c0 = *(const float4*)&cgs[gl[rt]][kt * 32 + quad * 8];
      const float4 c1 = *(const float4*)&cgs[gl[rt]][kt * 32 + quad * 8 + 4];
      const float h0 = fmaxf(bf2f(va.s[0]) + bf2f(vb.s[0]) + c0.x, 0.f);
      const float h1 = fmaxf(bf2f(va.s[1]) + bf2f(vb.s[1]) + c0.y, 0.f);
      const float h2 = fmaxf(bf2f(va.s[2]) + bf2f(vb.s[2]) + c0.z, 0.f);
      const float h3 = fmaxf(bf2f(va.s[3]) + bf2f(vb.s[3]) + c0.w, 0.f);
      const float h4 = fmaxf(bf2f(va.s[4]) + bf2f(vb.s[4]) + c1.x, 0.f);
      const float h5 = fmaxf(bf2f(va.s[5]) + bf2f(vb.s[5]) + c1.y, 0.f);
      const float h6 = fmaxf(bf2f(va.s[6]) + bf2f(vb.s[6]) + c1.z, 0.f);
      const float h7 = fmaxf(bf2f(va.s[7]) + bf2f(vb.s[7]) + c1.w, 0.f);
      union { short8 v; unsigned u[4]; } pk;
      pk.u[0] = pkbf(h0, h1);
      pk.u[1] = pkbf(h2, h3);
      pk.u[2] = pkbf(h4, h5);
      pk.u[3] = pkbf(h6, h7);
      A[rt][kt] = pk.v;
    }
  }

  f32x4 acc[2][4];
#pragma unroll
  for (int rt = 0; rt < 2; ++rt)
#pragma unroll
    for (int ct = 0; ct < 4; ++ct) acc[rt][ct] = (f32x4)(0.f);

#pragma unroll
  for (int kt = 0; kt < 4; ++kt) {
#pragma unroll
    for (int ct = 0; ct < 4; ++ct) {
      const short8 Bf = *(const short8*)(w2b + (size_t)(ct * 16 + col) * H +
                                         kt * 32 + quad * 8);
#pragma unroll
      for (int rt = 0; rt < 2; ++rt)
        acc[rt][ct] = __builtin_amdgcn_mfma_f32_16x16x32_bf16(
            A[rt][kt], Bf, acc[rt][ct], 0, 0, 0);
    }
  }

  // ---- epilogue: layer 3 + column reduction ----
  float b2v[4], w3v[4];
#pragma unroll
  for (int ct = 0; ct < 4; ++ct) {
    b2v[ct] = b2[ct * 16 + col];
    w3v[ct] = W3[ct * 16 + col];
  }
  const float bias3 = b3[0];
#pragma unroll
  for (int rt = 0; rt < 2; ++rt) {
#pragma unroll
    for (int reg = 0; reg < 4; ++reg) {
      float s = 0.f;
#pragma unroll
      for (int ct = 0; ct < 4; ++ct)
        s += fmaxf(acc[rt][ct][reg] + b2v[ct], 0.f) * w3v[ct];
      s += __shfl_xor(s, 1);
      s += __shfl_xor(s, 2);
      s += __shfl_xor(s, 4);
      s += __shfl_xor(s, 8);
      if (col == 0) {
        const int row = Rw + rt * 16 + quad * 4 + reg;   // C row = quad*4+reg
        if (row < N_ROWS) out[row] = s + bias3;
      }
    }
  }
}

// ---------------------------------------------------------------------------
extern "C" void kernel_launch(void* const* d_in, const int* in_sizes, int n_in,
                              void* d_out, int out_size, void* d_ws, size_t ws_size,
                              hipStream_t stream) {
  const int*   indices = (const int*)  d_in[0];
  // d_in[1] = nr (scalar, fixed at 24)
  const float* x  = (const float*)d_in[2];
  const float* W1 = (const float*)d_in[3];
  const float* b1 = (const float*)d_in[4];
  const float* W2 = (const float*)d_in[5];
  const float* b2 = (const float*)d_in[6];
  const float* W3 = (const float*)d_in[7];
  const float* b3 = (const float*)d_in[8];
  float* out = (float*)d_out;

  // Workspace: Pb (bf16 3*10000*128 = 7.68 MB) | w2b (bf16 64*128 = 16 KB)
  unsigned short* Pb  = (unsigned short*)d_ws;
  unsigned short* P1b = Pb;
  unsigned short* P2b = Pb + (size_t)NODES * H;
  unsigned short* P3b = Pb + (size_t)2 * NODES * H;
  unsigned short* w2b = Pb + (size_t)3 * NODES * H;

  dim3 gpre((NODES + PN - 1) / PN, 3);
  k_precompute<<<gpre, 256, 0, stream>>>(x, W1, W2, Pb, w2b);
  k_main<<<(N_ROWS + 127) / 128, 256, 0, stream>>>(indices, P1b, P2b, P3b, w2b,
                                                   b1, b2, W3, b3, out);
}

// Round 7
// 239.765 us; speedup vs baseline: 1.0141x; 1.0141x over previous
//
#include <hip/hip_runtime.h>
#include <hip/hip_bf16.h>

// Problem constants (fixed by the reference setup)
#define N_ROWS   500000
#define NR1      25        // nr + 1
#define NGROUPS  20000     // N_ROWS / NR1
#define KCTX     20        // K context indices
#define H        128
#define NODES    10000
#define IDX_COLS 23        // 3 + K

typedef __attribute__((ext_vector_type(8))) short short8;   // 8 bf16 = 4 VGPRs
typedef __attribute__((ext_vector_type(4))) float f32x4;    // MFMA C/D

// pack two floats -> two bf16 (RNE) as a 32-bit word
__device__ __forceinline__ unsigned pkbf(float lo, float hi) {
  __hip_bfloat162 h = __float22bfloat162_rn(make_float2(lo, hi));
  union { __hip_bfloat162 h; unsigned u; } c; c.h = h;
  return c.u;
}
__device__ __forceinline__ float bf2f(unsigned short u) {
  union { unsigned u; float f; } c; c.u = ((unsigned)u) << 16; return c.f;
}

// ---------------------------------------------------------------------------
// Kernel A (v4): P[m] = x @ W1m.T via single-bf16 MFMA, P stored bf16.
// (bf16 rounding of W1/x/P verified harmless: absmax stayed 1.22e-4 in R4/R5;
// downstream W2*W3 attenuates P-level noise ~25x.)
// Grid (157, 3), block 256 = 4 waves; wave owns 16 nodes. LDS 34.8 KB.
// ---------------------------------------------------------------------------
#define PN 64
__global__ __launch_bounds__(256) void k_precompute(
    const float* __restrict__ x, const float* __restrict__ W1,
    unsigned short* __restrict__ Pb) {
  __shared__ short wlds[128][136];   // bf16 W1m[j][k], padded: 34.8 KB

  const int tid   = threadIdx.x;
  const int m     = blockIdx.y;            // 0..2
  const int tbase = blockIdx.x * PN;       // node tile base

  // ---- stage W1m -> LDS bf16 (coalesced float4 reads) ----
#pragma unroll
  for (int it = 0; it < 16; ++it) {
    const int f  = it * 256 + tid;         // 0..4095 float4s (128 j x 32)
    const int j  = f >> 5;
    const int q4 = f & 31;
    const float4 v = *(const float4*)(W1 + (size_t)j * (3 * H) + m * H + q4 * 4);
    *(unsigned*)&wlds[j][q4 * 4]     = pkbf(v.x, v.y);
    *(unsigned*)&wlds[j][q4 * 4 + 2] = pkbf(v.z, v.w);
  }
  __syncthreads();

  const int lane = tid & 63;
  const int wv   = tid >> 6;
  const int col  = lane & 15;
  const int quad = lane >> 4;

  int node = tbase + wv * 16 + col;
  if (node > NODES - 1) node = NODES - 1;
  const float4* __restrict__ xr = (const float4*)(x + (size_t)node * H);

  short8 Af[4];
#pragma unroll
  for (int kt = 0; kt < 4; ++kt) {
    const int f4 = kt * 8 + quad * 2;
    const float4 v0 = xr[f4], v1 = xr[f4 + 1];
    union { short8 v; unsigned u[4]; } pk;
    pk.u[0] = pkbf(v0.x, v0.y);
    pk.u[1] = pkbf(v0.z, v0.w);
    pk.u[2] = pkbf(v1.x, v1.y);
    pk.u[3] = pkbf(v1.z, v1.w);
    Af[kt] = pk.v;
  }

  f32x4 acc[8];
#pragma unroll
  for (int ct = 0; ct < 8; ++ct) acc[ct] = (f32x4)(0.f);

#pragma unroll
  for (int kt = 0; kt < 4; ++kt) {
#pragma unroll
    for (int ct = 0; ct < 8; ++ct) {
      const short8 Bf = *(const short8*)&wlds[ct * 16 + col][kt * 32 + quad * 8];
      acc[ct] = __builtin_amdgcn_mfma_f32_16x16x32_bf16(Af[kt], Bf, acc[ct], 0, 0, 0);
    }
  }

  // ---- write P[m] bf16; C row = quad*4+reg, col = ct*16 + (lane&15) ----
  unsigned short* __restrict__ Pm = Pb + (size_t)m * NODES * H;
#pragma unroll
  for (int reg = 0; reg < 4; ++reg) {
    const int n = tbase + wv * 16 + quad * 4 + reg;
    if (n < NODES) {
#pragma unroll
      for (int ct = 0; ct < 8; ++ct) {
        union { unsigned u; unsigned short s[2]; } c;
        c.u = pkbf(acc[ct][reg], 0.f);
        Pm[(size_t)n * H + ct * 16 + col] = c.s[0];
      }
    }
  }
}

// ---------------------------------------------------------------------------
// Kernel C (v6): fused main kernel — R4 structure (W2 in LDS) + prefetch-first.
//  Phase A:  issue ALL P1/P2 short8 gathers immediately (latency overlaps
//            phases 0a/0b; vmcnt FIFO drains them by the ctx phase's waits).
//  Phase 0a: W2 -> LDS bf16 (w2s[n][k], padded; broadcast-friendly B-frags).
//  Phase 0b: <=7 context-group rows -> cgs LDS (b1 folded, /norm applied).
//  Phase C:  combine into bf16 A-fragments; 16x16x32 MFMA layer 2.
//  Epilogue: layer 3 + shfl_xor column reduction.
// Block = 256 threads (4 waves), 128 rows; wave w owns rows [w*32, +32).
// ---------------------------------------------------------------------------
__global__ __launch_bounds__(256) void k_main(
    const int* __restrict__ indices,
    const unsigned short* __restrict__ P1b, const unsigned short* __restrict__ P2b,
    const unsigned short* __restrict__ P3b,
    const float* __restrict__ W2, const float* __restrict__ b1,
    const float* __restrict__ b2, const float* __restrict__ W3,
    const float* __restrict__ b3, float* __restrict__ out) {
  __shared__ short w2s[64][136];   // bf16 W2[n][k], padded: 17.4 KB
  __shared__ float cgs[7][132];    // context rows (b1 folded), padded: 3.7 KB

  const int tid   = threadIdx.x;
  const int rbase = blockIdx.x * 128;
  const int gbase = rbase / NR1;

  const int lane = tid & 63;
  const int wv   = tid >> 6;
  const int col  = lane & 15;
  const int quad = lane >> 4;
  const int Rw   = rbase + wv * 32;

  // ---- phase A: issue raw P1/P2 gathers up front ----
  int gl[2];
  short8 ua[2][4], ub[2][4];
#pragma unroll
  for (int rt = 0; rt < 2; ++rt) {
    const int r  = Rw + rt * 16 + col;
    const int rc = (r < N_ROWS) ? r : (N_ROWS - 1);
    const int i0 = indices[(size_t)rc * IDX_COLS + 0];
    const int i1 = indices[(size_t)rc * IDX_COLS + 1];
    const short8* __restrict__ pa = (const short8*)(P1b + (size_t)i0 * H);
    const short8* __restrict__ pb = (const short8*)(P2b + (size_t)i1 * H);
#pragma unroll
    for (int kt = 0; kt < 4; ++kt) {
      ua[rt][kt] = pa[kt * 4 + quad];
      ub[rt][kt] = pb[kt * 4 + quad];
    }
    gl[rt] = rc / NR1 - gbase;
  }

  // ---- phase 0a: W2 -> LDS bf16 (overlaps gather latency) ----
  for (int idx = tid; idx < 64 * 64; idx += 256) {
    const int n  = idx >> 6;        // row 0..63
    const int kp = idx & 63;        // k-pair 0..63
    const float2 w = *(const float2*)(W2 + (size_t)n * H + kp * 2);
    *(unsigned*)&w2s[n][kp * 2] = pkbf(w.x, w.y);
  }

  // ---- phase 0b: context groups for this block (overlaps gather latency) ----
  {
    int rlast = rbase + 127; if (rlast > N_ROWS - 1) rlast = N_ROWS - 1;
    const int G   = rlast / NR1 - gbase + 1;   // <= 7
    const int j   = tid & 127;
    const int sub = tid >> 7;
#pragma unroll
    for (int it = 0; it < 4; ++it) {
      const int gi = it * 2 + sub;
      if (gi < G) {
        const int* __restrict__ rowidx =
            indices + (size_t)(gbase + gi) * NR1 * IDX_COLS + 3;
        float s = 0.f; int cnt = 0;
#pragma unroll
        for (int c = 0; c < KCTX; ++c) {
          const int idx = rowidx[c];
          s += bf2f(P3b[(size_t)idx * H + j]);
          cnt += (idx > 0) ? 1 : 0;
        }
        const float norm = (float)((cnt > 1) ? cnt : 1);
        cgs[gi][j] = b1[j] + s / norm;
      }
    }
  }
  __syncthreads();

  // ---- phase C: combine into A-fragments (bf16), MFMA layer 2 ----
  short8 A[2][4];
#pragma unroll
  for (int rt = 0; rt < 2; ++rt) {
#pragma unroll
    for (int kt = 0; kt < 4; ++kt) {
      union { short8 v; unsigned short s[8]; } va, vb;
      va.v = ua[rt][kt];
      vb.v = ub[rt][kt];
      const float4 c0 = *(const float4*)&cgs[gl[rt]][kt * 32 + quad * 8];
      const float4 c1 = *(const float4*)&cgs[gl[rt]][kt * 32 + quad * 8 + 4];
      const float h0 = fmaxf(bf2f(va.s[0]) + bf2f(vb.s[0]) + c0.x, 0.f);
      const float h1 = fmaxf(bf2f(va.s[1]) + bf2f(vb.s[1]) + c0.y, 0.f);
      const float h2 = fmaxf(bf2f(va.s[2]) + bf2f(vb.s[2]) + c0.z, 0.f);
      const float h3 = fmaxf(bf2f(va.s[3]) + bf2f(vb.s[3]) + c0.w, 0.f);
      const float h4 = fmaxf(bf2f(va.s[4]) + bf2f(vb.s[4]) + c1.x, 0.f);
      const float h5 = fmaxf(bf2f(va.s[5]) + bf2f(vb.s[5]) + c1.y, 0.f);
      const float h6 = fmaxf(bf2f(va.s[6]) + bf2f(vb.s[6]) + c1.z, 0.f);
      const float h7 = fmaxf(bf2f(va.s[7]) + bf2f(vb.s[7]) + c1.w, 0.f);
      union { short8 v; unsigned u[4]; } pk;
      pk.u[0] = pkbf(h0, h1);
      pk.u[1] = pkbf(h2, h3);
      pk.u[2] = pkbf(h4, h5);
      pk.u[3] = pkbf(h6, h7);
      A[rt][kt] = pk.v;
    }
  }

  f32x4 acc[2][4];
#pragma unroll
  for (int rt = 0; rt < 2; ++rt)
#pragma unroll
    for (int ct = 0; ct < 4; ++ct) acc[rt][ct] = (f32x4)(0.f);

#pragma unroll
  for (int kt = 0; kt < 4; ++kt) {
#pragma unroll
    for (int ct = 0; ct < 4; ++ct) {
      const short8 Bf = *(const short8*)&w2s[ct * 16 + col][kt * 32 + quad * 8];
#pragma unroll
      for (int rt = 0; rt < 2; ++rt)
        acc[rt][ct] = __builtin_amdgcn_mfma_f32_16x16x32_bf16(
            A[rt][kt], Bf, acc[rt][ct], 0, 0, 0);
    }
  }

  // ---- epilogue: layer 3 + column reduction ----
  float b2v[4], w3v[4];
#pragma unroll
  for (int ct = 0; ct < 4; ++ct) {
    b2v[ct] = b2[ct * 16 + col];
    w3v[ct] = W3[ct * 16 + col];
  }
  const float bias3 = b3[0];
#pragma unroll
  for (int rt = 0; rt < 2; ++rt) {
#pragma unroll
    for (int reg = 0; reg < 4; ++reg) {
      float s = 0.f;
#pragma unroll
      for (int ct = 0; ct < 4; ++ct)
        s += fmaxf(acc[rt][ct][reg] + b2v[ct], 0.f) * w3v[ct];
      s += __shfl_xor(s, 1);
      s += __shfl_xor(s, 2);
      s += __shfl_xor(s, 4);
      s += __shfl_xor(s, 8);
      if (col == 0) {
        const int row = Rw + rt * 16 + quad * 4 + reg;   // C row = quad*4+reg
        if (row < N_ROWS) out[row] = s + bias3;
      }
    }
  }
}

// ---------------------------------------------------------------------------
extern "C" void kernel_launch(void* const* d_in, const int* in_sizes, int n_in,
                              void* d_out, int out_size, void* d_ws, size_t ws_size,
                              hipStream_t stream) {
  const int*   indices = (const int*)  d_in[0];
  // d_in[1] = nr (scalar, fixed at 24)
  const float* x  = (const float*)d_in[2];
  const float* W1 = (const float*)d_in[3];
  const float* b1 = (const float*)d_in[4];
  const float* W2 = (const float*)d_in[5];
  const float* b2 = (const float*)d_in[6];
  const float* W3 = (const float*)d_in[7];
  const float* b3 = (const float*)d_in[8];
  float* out = (float*)d_out;

  // Workspace: Pb (bf16 3*10000*128 = 7.68 MB)
  unsigned short* Pb  = (unsigned short*)d_ws;
  unsigned short* P1b = Pb;
  unsigned short* P2b = Pb + (size_t)NODES * H;
  unsigned short* P3b = Pb + (size_t)2 * NODES * H;

  dim3 gpre((NODES + PN - 1) / PN, 3);
  k_precompute<<<gpre, 256, 0, stream>>>(x, W1, Pb);
  k_main<<<(N_ROWS + 127) / 128, 256, 0, stream>>>(indices, P1b, P2b, P3b,
                                                   W2, b1, b2, W3, b3, out);
}

// Round 8
// 233.249 us; speedup vs baseline: 1.0424x; 1.0279x over previous
//
#include <hip/hip_runtime.h>
#include <hip/hip_bf16.h>

// Problem constants (fixed by the reference setup)
#define N_ROWS   500000
#define NR1      25        // nr + 1
#define NGROUPS  20000     // N_ROWS / NR1
#define KCTX     20        // K context indices
#define H        128
#define NODES    10000
#define IDX_COLS 23        // 3 + K

#define RPB      128                 // rows per k_main block
#define IL_INTS  (RPB * IDX_COLS)    // 2944 ints staged per block
#define IL_F4    (IL_INTS / 4)       // 736 float4s (RPB*23*4 % 16 == 0)
#define TOT_F4   (N_ROWS * IDX_COLS / 4)  // 2,875,000

typedef __attribute__((ext_vector_type(8))) short short8;   // 8 bf16 = 4 VGPRs
typedef __attribute__((ext_vector_type(4))) float f32x4;    // MFMA C/D

// pack two floats -> two bf16 (RNE) as a 32-bit word
__device__ __forceinline__ unsigned pkbf(float lo, float hi) {
  __hip_bfloat162 h = __float22bfloat162_rn(make_float2(lo, hi));
  union { __hip_bfloat162 h; unsigned u; } c; c.h = h;
  return c.u;
}
__device__ __forceinline__ float bf2f(unsigned short u) {
  union { unsigned u; float f; } c; c.u = ((unsigned)u) << 16; return c.f;
}

// ---------------------------------------------------------------------------
// Kernel A (v4): P[m] = x @ W1m.T via single-bf16 MFMA, P stored bf16.
// (bf16 rounding of W1/x/P verified harmless across R4-R6: absmax 1.22e-4.)
// Grid (157, 3), block 256 = 4 waves; wave owns 16 nodes. LDS 34.8 KB.
// ---------------------------------------------------------------------------
#define PN 64
__global__ __launch_bounds__(256) void k_precompute(
    const float* __restrict__ x, const float* __restrict__ W1,
    unsigned short* __restrict__ Pb) {
  __shared__ short wlds[128][136];   // bf16 W1m[j][k], padded: 34.8 KB

  const int tid   = threadIdx.x;
  const int m     = blockIdx.y;            // 0..2
  const int tbase = blockIdx.x * PN;       // node tile base

#pragma unroll
  for (int it = 0; it < 16; ++it) {
    const int f  = it * 256 + tid;         // 0..4095 float4s (128 j x 32)
    const int j  = f >> 5;
    const int q4 = f & 31;
    const float4 v = *(const float4*)(W1 + (size_t)j * (3 * H) + m * H + q4 * 4);
    *(unsigned*)&wlds[j][q4 * 4]     = pkbf(v.x, v.y);
    *(unsigned*)&wlds[j][q4 * 4 + 2] = pkbf(v.z, v.w);
  }
  __syncthreads();

  const int lane = tid & 63;
  const int wv   = tid >> 6;
  const int col  = lane & 15;
  const int quad = lane >> 4;

  int node = tbase + wv * 16 + col;
  if (node > NODES - 1) node = NODES - 1;
  const float4* __restrict__ xr = (const float4*)(x + (size_t)node * H);

  short8 Af[4];
#pragma unroll
  for (int kt = 0; kt < 4; ++kt) {
    const int f4 = kt * 8 + quad * 2;
    const float4 v0 = xr[f4], v1 = xr[f4 + 1];
    union { short8 v; unsigned u[4]; } pk;
    pk.u[0] = pkbf(v0.x, v0.y);
    pk.u[1] = pkbf(v0.z, v0.w);
    pk.u[2] = pkbf(v1.x, v1.y);
    pk.u[3] = pkbf(v1.z, v1.w);
    Af[kt] = pk.v;
  }

  f32x4 acc[8];
#pragma unroll
  for (int ct = 0; ct < 8; ++ct) acc[ct] = (f32x4)(0.f);

#pragma unroll
  for (int kt = 0; kt < 4; ++kt) {
#pragma unroll
    for (int ct = 0; ct < 8; ++ct) {
      const short8 Bf = *(const short8*)&wlds[ct * 16 + col][kt * 32 + quad * 8];
      acc[ct] = __builtin_amdgcn_mfma_f32_16x16x32_bf16(Af[kt], Bf, acc[ct], 0, 0, 0);
    }
  }

  unsigned short* __restrict__ Pm = Pb + (size_t)m * NODES * H;
#pragma unroll
  for (int reg = 0; reg < 4; ++reg) {
    const int n = tbase + wv * 16 + quad * 4 + reg;
    if (n < NODES) {
#pragma unroll
      for (int ct = 0; ct < 8; ++ct) {
        union { unsigned u; unsigned short s[2]; } c;
        c.u = pkbf(acc[ct][reg], 0.f);
        Pm[(size_t)n * H + ct * 16 + col] = c.s[0];
      }
    }
  }
}

// ---------------------------------------------------------------------------
// Kernel C (v7): fused main kernel.
//  Pre-barrier (coalesced, no gather interference):
//    - stage this block's 128 index rows (2944 ints) -> il LDS, float4 reads
//    - stage W2 -> w2s LDS bf16
//  barrier 1
//    - read i0/i1 from il (broadcast, stride-23 coprime to 32 banks)
//    - ISSUE all 16 P1/P2 short8 gathers -> ua/ub registers
//    - ctx phase (group rows -> cgs; its P3 gathers overlap ours in vmcnt)
//  barrier 2
//    - A-fragments (bf16), 16x16x32 MFMA layer 2, layer-3 epilogue
// Block = 256 threads (4 waves), 128 rows; wave w owns rows [w*32, +32).
// ---------------------------------------------------------------------------
__global__ __launch_bounds__(256) void k_main(
    const int* __restrict__ indices,
    const unsigned short* __restrict__ P1b, const unsigned short* __restrict__ P2b,
    const unsigned short* __restrict__ P3b,
    const float* __restrict__ W2, const float* __restrict__ b1,
    const float* __restrict__ b2, const float* __restrict__ W3,
    const float* __restrict__ b3, float* __restrict__ out) {
  __shared__ __align__(16) int   il[IL_INTS];   // 11.8 KB index stage
  __shared__ __align__(16) short w2s[64][136];  // bf16 W2[n][k]: 17.4 KB
  __shared__ float cgs[7][132];                 // ctx rows (b1 folded): 3.7 KB

  const int tid   = threadIdx.x;
  const int rbase = blockIdx.x * RPB;
  const int gbase = rbase / NR1;

  // ---- pre-barrier: coalesced index staging ----
  {
    const int base = IL_F4 * blockIdx.x;
    const int lim  = TOT_F4 - base;           // < IL_F4 only for last block
    const float4* __restrict__ src = (const float4*)indices + base;
#pragma unroll
    for (int it = 0; it < 3; ++it) {
      const int i = it * 256 + tid;
      if (i < IL_F4 && i < lim) ((float4*)il)[i] = src[i];
    }
  }
  // ---- pre-barrier: W2 -> LDS bf16 (coalesced float2 reads) ----
  for (int idx = tid; idx < 64 * 64; idx += 256) {
    const int n  = idx >> 6;        // row 0..63
    const int kp = idx & 63;        // k-pair 0..63
    const float2 w = *(const float2*)(W2 + (size_t)n * H + kp * 2);
    *(unsigned*)&w2s[n][kp * 2] = pkbf(w.x, w.y);
  }
  __syncthreads();

  const int lane = tid & 63;
  const int wv   = tid >> 6;
  const int col  = lane & 15;
  const int quad = lane >> 4;
  const int Rw   = rbase + wv * 32;

  // ---- issue all P1/P2 gathers (addresses from LDS, fast) ----
  int gl[2];
  short8 ua[2][4], ub[2][4];
#pragma unroll
  for (int rt = 0; rt < 2; ++rt) {
    const int r    = Rw + rt * 16 + col;
    const int rc   = (r < N_ROWS) ? r : (N_ROWS - 1);
    const int lrow = rc - rbase;              // in [0, RPB)
    const int i0   = il[lrow * IDX_COLS + 0];
    const int i1   = il[lrow * IDX_COLS + 1];
    const short8* __restrict__ pa = (const short8*)(P1b + (size_t)i0 * H);
    const short8* __restrict__ pb = (const short8*)(P2b + (size_t)i1 * H);
#pragma unroll
    for (int kt = 0; kt < 4; ++kt) {
      ua[rt][kt] = pa[kt * 4 + quad];
      ub[rt][kt] = pb[kt * 4 + quad];
    }
    gl[rt] = rc / NR1 - gbase;
  }

  // ---- ctx phase (overlaps the in-flight gathers) ----
  {
    int rlast = rbase + RPB - 1; if (rlast > N_ROWS - 1) rlast = N_ROWS - 1;
    const int G   = rlast / NR1 - gbase + 1;   // <= 7
    const int j   = tid & 127;
    const int sub = tid >> 7;
#pragma unroll
    for (int it = 0; it < 4; ++it) {
      const int gi = it * 2 + sub;
      if (gi < G) {
        const int* __restrict__ rowidx =
            indices + (size_t)(gbase + gi) * NR1 * IDX_COLS + 3;
        float s = 0.f; int cnt = 0;
#pragma unroll
        for (int c = 0; c < KCTX; ++c) {
          const int idx = rowidx[c];
          s += bf2f(P3b[(size_t)idx * H + j]);
          cnt += (idx > 0) ? 1 : 0;
        }
        const float norm = (float)((cnt > 1) ? cnt : 1);
        cgs[gi][j] = b1[j] + s / norm;
      }
    }
  }
  __syncthreads();

  // ---- A-fragments (bf16) + MFMA layer 2 ----
  short8 A[2][4];
#pragma unroll
  for (int rt = 0; rt < 2; ++rt) {
#pragma unroll
    for (int kt = 0; kt < 4; ++kt) {
      union { short8 v; unsigned short s[8]; } va, vb;
      va.v = ua[rt][kt];
      vb.v = ub[rt][kt];
      const float4 c0 = *(const float4*)&cgs[gl[rt]][kt * 32 + quad * 8];
      const float4 c1 = *(const float4*)&cgs[gl[rt]][kt * 32 + quad * 8 + 4];
      const float h0 = fmaxf(bf2f(va.s[0]) + bf2f(vb.s[0]) + c0.x, 0.f);
      const float h1 = fmaxf(bf2f(va.s[1]) + bf2f(vb.s[1]) + c0.y, 0.f);
      const float h2 = fmaxf(bf2f(va.s[2]) + bf2f(vb.s[2]) + c0.z, 0.f);
      const float h3 = fmaxf(bf2f(va.s[3]) + bf2f(vb.s[3]) + c0.w, 0.f);
      const float h4 = fmaxf(bf2f(va.s[4]) + bf2f(vb.s[4]) + c1.x, 0.f);
      const float h5 = fmaxf(bf2f(va.s[5]) + bf2f(vb.s[5]) + c1.y, 0.f);
      const float h6 = fmaxf(bf2f(va.s[6]) + bf2f(vb.s[6]) + c1.z, 0.f);
      const float h7 = fmaxf(bf2f(va.s[7]) + bf2f(vb.s[7]) + c1.w, 0.f);
      union { short8 v; unsigned u[4]; } pk;
      pk.u[0] = pkbf(h0, h1);
      pk.u[1] = pkbf(h2, h3);
      pk.u[2] = pkbf(h4, h5);
      pk.u[3] = pkbf(h6, h7);
      A[rt][kt] = pk.v;
    }
  }

  f32x4 acc[2][4];
#pragma unroll
  for (int rt = 0; rt < 2; ++rt)
#pragma unroll
    for (int ct = 0; ct < 4; ++ct) acc[rt][ct] = (f32x4)(0.f);

#pragma unroll
  for (int kt = 0; kt < 4; ++kt) {
#pragma unroll
    for (int ct = 0; ct < 4; ++ct) {
      const short8 Bf = *(const short8*)&w2s[ct * 16 + col][kt * 32 + quad * 8];
#pragma unroll
      for (int rt = 0; rt < 2; ++rt)
        acc[rt][ct] = __builtin_amdgcn_mfma_f32_16x16x32_bf16(
            A[rt][kt], Bf, acc[rt][ct], 0, 0, 0);
    }
  }

  // ---- epilogue: layer 3 + column reduction ----
  float b2v[4], w3v[4];
#pragma unroll
  for (int ct = 0; ct < 4; ++ct) {
    b2v[ct] = b2[ct * 16 + col];
    w3v[ct] = W3[ct * 16 + col];
  }
  const float bias3 = b3[0];
#pragma unroll
  for (int rt = 0; rt < 2; ++rt) {
#pragma unroll
    for (int reg = 0; reg < 4; ++reg) {
      float s = 0.f;
#pragma unroll
      for (int ct = 0; ct < 4; ++ct)
        s += fmaxf(acc[rt][ct][reg] + b2v[ct], 0.f) * w3v[ct];
      s += __shfl_xor(s, 1);
      s += __shfl_xor(s, 2);
      s += __shfl_xor(s, 4);
      s += __shfl_xor(s, 8);
      if (col == 0) {
        const int row = Rw + rt * 16 + quad * 4 + reg;   // C row = quad*4+reg
        if (row < N_ROWS) out[row] = s + bias3;
      }
    }
  }
}

// ---------------------------------------------------------------------------
extern "C" void kernel_launch(void* const* d_in, const int* in_sizes, int n_in,
                              void* d_out, int out_size, void* d_ws, size_t ws_size,
                              hipStream_t stream) {
  const int*   indices = (const int*)  d_in[0];
  // d_in[1] = nr (scalar, fixed at 24)
  const float* x  = (const float*)d_in[2];
  const float* W1 = (const float*)d_in[3];
  const float* b1 = (const float*)d_in[4];
  const float* W2 = (const float*)d_in[5];
  const float* b2 = (const float*)d_in[6];
  const float* W3 = (const float*)d_in[7];
  const float* b3 = (const float*)d_in[8];
  float* out = (float*)d_out;

  // Workspace: Pb (bf16 3*10000*128 = 7.68 MB)
  unsigned short* Pb  = (unsigned short*)d_ws;
  unsigned short* P1b = Pb;
  unsigned short* P2b = Pb + (size_t)NODES * H;
  unsigned short* P3b = Pb + (size_t)2 * NODES * H;

  dim3 gpre((NODES + PN - 1) / PN, 3);
  k_precompute<<<gpre, 256, 0, stream>>>(x, W1, Pb);
  k_main<<<(N_ROWS + RPB - 1) / RPB, 256, 0, stream>>>(indices, P1b, P2b, P3b,
                                                       W2, b1, b2, W3, b3, out);
}

// Round 9
// 197.590 us; speedup vs baseline: 1.2306x; 1.1805x over previous
//
#include <hip/hip_runtime.h>
#include <hip/hip_bf16.h>

// Problem constants (fixed by the reference setup)
#define N_ROWS   500000
#define NR1      25        // nr + 1
#define NGROUPS  20000     // N_ROWS / NR1
#define KCTX     20        // K context indices
#define H        128
#define NODES    10000
#define IDX_COLS 23        // 3 + K

#define RPB      128       // rows per k_main block (32 per wave)

typedef __attribute__((ext_vector_type(8))) short short8;   // 8 bf16 = 4 VGPRs
typedef __attribute__((ext_vector_type(4))) float f32x4;    // MFMA C/D

// pack two floats -> two bf16 (RNE) as a 32-bit word
__device__ __forceinline__ unsigned pkbf(float lo, float hi) {
  __hip_bfloat162 h = __float22bfloat162_rn(make_float2(lo, hi));
  union { __hip_bfloat162 h; unsigned u; } c; c.h = h;
  return c.u;
}
__device__ __forceinline__ float bf2f(unsigned short u) {
  union { unsigned u; float f; } c; c.u = ((unsigned)u) << 16; return c.f;
}

// ---------------------------------------------------------------------------
// Kernel P: pack (i0,i1) -> idx2 (coalesced main-kernel reads), and block 0
// additionally permutes W2 into bf16 MFMA B-fragment layout:
//   w2f[(kt*4+ct)*64 + lane] = bf16{ W2[ct*16+(lane&15)][kt*32+(lane>>4)*8 + j] }
// so k_main's B loads are contiguous 16 B per lane (1 KB/wave, L1-resident).
// ---------------------------------------------------------------------------
__global__ __launch_bounds__(256) void k_pack(
    const int* __restrict__ indices, const float* __restrict__ W2,
    int2* __restrict__ idx2, short8* __restrict__ w2f) {
  const int r = blockIdx.x * 256 + threadIdx.x;
  if (r < N_ROWS) {
    idx2[r] = make_int2(indices[(size_t)r * IDX_COLS + 0],
                        indices[(size_t)r * IDX_COLS + 1]);
  }
  if (blockIdx.x == 0) {
#pragma unroll
    for (int it = 0; it < 4; ++it) {
      const int id   = it * 256 + threadIdx.x;   // 0..1023
      const int f    = id >> 6;                  // kt*4+ct
      const int l    = id & 63;
      const int kt   = f >> 2, ct = f & 3;
      const int col  = l & 15, quad = l >> 4;
      const float* __restrict__ src =
          W2 + (size_t)(ct * 16 + col) * H + kt * 32 + quad * 8;
      const float4 v0 = *(const float4*)src;
      const float4 v1 = *(const float4*)(src + 4);
      union { short8 v; unsigned u[4]; } pk;
      pk.u[0] = pkbf(v0.x, v0.y);
      pk.u[1] = pkbf(v0.z, v0.w);
      pk.u[2] = pkbf(v1.x, v1.y);
      pk.u[3] = pkbf(v1.z, v1.w);
      w2f[id] = pk.v;
    }
  }
}

// ---------------------------------------------------------------------------
// Kernel A (v4): P[m] = x @ W1m.T via single-bf16 MFMA, P stored bf16.
// (bf16 rounding of W1/x/P verified harmless across R4-R7: absmax 1.22e-4.)
// ---------------------------------------------------------------------------
#define PN 64
__global__ __launch_bounds__(256) void k_precompute(
    const float* __restrict__ x, const float* __restrict__ W1,
    unsigned short* __restrict__ Pb) {
  __shared__ short wlds[128][136];   // bf16 W1m[j][k], padded: 34.8 KB

  const int tid   = threadIdx.x;
  const int m     = blockIdx.y;            // 0..2
  const int tbase = blockIdx.x * PN;       // node tile base

#pragma unroll
  for (int it = 0; it < 16; ++it) {
    const int f  = it * 256 + tid;         // 0..4095 float4s (128 j x 32)
    const int j  = f >> 5;
    const int q4 = f & 31;
    const float4 v = *(const float4*)(W1 + (size_t)j * (3 * H) + m * H + q4 * 4);
    *(unsigned*)&wlds[j][q4 * 4]     = pkbf(v.x, v.y);
    *(unsigned*)&wlds[j][q4 * 4 + 2] = pkbf(v.z, v.w);
  }
  __syncthreads();

  const int lane = tid & 63;
  const int wv   = tid >> 6;
  const int col  = lane & 15;
  const int quad = lane >> 4;

  int node = tbase + wv * 16 + col;
  if (node > NODES - 1) node = NODES - 1;
  const float4* __restrict__ xr = (const float4*)(x + (size_t)node * H);

  short8 Af[4];
#pragma unroll
  for (int kt = 0; kt < 4; ++kt) {
    const int f4 = kt * 8 + quad * 2;
    const float4 v0 = xr[f4], v1 = xr[f4 + 1];
    union { short8 v; unsigned u[4]; } pk;
    pk.u[0] = pkbf(v0.x, v0.y);
    pk.u[1] = pkbf(v0.z, v0.w);
    pk.u[2] = pkbf(v1.x, v1.y);
    pk.u[3] = pkbf(v1.z, v1.w);
    Af[kt] = pk.v;
  }

  f32x4 acc[8];
#pragma unroll
  for (int ct = 0; ct < 8; ++ct) acc[ct] = (f32x4)(0.f);

#pragma unroll
  for (int kt = 0; kt < 4; ++kt) {
#pragma unroll
    for (int ct = 0; ct < 8; ++ct) {
      const short8 Bf = *(const short8*)&wlds[ct * 16 + col][kt * 32 + quad * 8];
      acc[ct] = __builtin_amdgcn_mfma_f32_16x16x32_bf16(Af[kt], Bf, acc[ct], 0, 0, 0);
    }
  }

  unsigned short* __restrict__ Pm = Pb + (size_t)m * NODES * H;
#pragma unroll
  for (int reg = 0; reg < 4; ++reg) {
    const int n = tbase + wv * 16 + quad * 4 + reg;
    if (n < NODES) {
#pragma unroll
      for (int ct = 0; ct < 8; ++ct) {
        union { unsigned u; unsigned short s[2]; } c;
        c.u = pkbf(acc[ct][reg], 0.f);
        Pm[(size_t)n * H + ct * 16 + col] = c.s[0];
      }
    }
  }
}

// ---------------------------------------------------------------------------
// Kernel C (v8): BARRIER-FREE fused main kernel. Waves fully autonomous:
//   - P1/P2 gathers issued first (overlap ctx compute, no barrier to drain)
//   - ctx-group rows computed PER WAVE into a wave-private LDS slab
//     (same-wave DS ordering: no __syncthreads, just lgkmcnt)
//   - B-fragments from pre-permuted w2f global (coalesced 16 B/lane, L1-hot)
// Rationale: R5/R6/R7 all showed the s_waitcnt vmcnt(0)+s_barrier pair turns
// per-wave gather latency into per-block max (147 vs 78 us). Zero barriers.
// Block = 256 threads (4 waves), 128 rows; wave w owns rows [w*32, +32).
// ---------------------------------------------------------------------------
__global__ __launch_bounds__(256) void k_main(
    const int2* __restrict__ idx2, const int* __restrict__ indices,
    const unsigned short* __restrict__ P1b, const unsigned short* __restrict__ P2b,
    const unsigned short* __restrict__ P3b, const short8* __restrict__ w2f,
    const float* __restrict__ b1, const float* __restrict__ b2,
    const float* __restrict__ W3, const float* __restrict__ b3,
    float* __restrict__ out) {
  __shared__ float cgs[4][3][128];   // per-WAVE ctx slabs (b1 folded): 6 KB

  const int tid   = threadIdx.x;
  const int rbase = blockIdx.x * RPB;

  const int lane = tid & 63;
  const int wv   = tid >> 6;
  const int col  = lane & 15;
  const int quad = lane >> 4;
  const int Rw   = rbase + wv * 32;

  // group range for this wave's 32 rows (clamped)
  const int r0c  = (Rw     < N_ROWS) ? Rw          : (N_ROWS - 1);
  const int rLc  = (Rw + 31 < N_ROWS) ? (Rw + 31)  : (N_ROWS - 1);
  const int g_lo = r0c / NR1;
  const int ng   = rLc / NR1 - g_lo + 1;          // 1..3

  // ---- phase 1: issue all P1/P2 gathers (no barrier will gate them) ----
  int gl[2];
  short8 ua[2][4], ub[2][4];
#pragma unroll
  for (int rt = 0; rt < 2; ++rt) {
    const int r  = Rw + rt * 16 + col;
    const int rc = (r < N_ROWS) ? r : (N_ROWS - 1);
    const int2 ii = idx2[rc];
    const short8* __restrict__ pa = (const short8*)(P1b + (size_t)ii.x * H);
    const short8* __restrict__ pb = (const short8*)(P2b + (size_t)ii.y * H);
#pragma unroll
    for (int kt = 0; kt < 4; ++kt) {
      ua[rt][kt] = pa[kt * 4 + quad];
      ub[rt][kt] = pb[kt * 4 + quad];
    }
    gl[rt] = rc / NR1 - g_lo;
  }

  // ---- phase 2: per-wave ctx rows (lane covers cols 2*lane, 2*lane+1) ----
  {
    const int jj = lane * 2;
    const float2 b1v = *(const float2*)(b1 + jj);
#pragma unroll
    for (int gi = 0; gi < 3; ++gi) {
      if (gi < ng) {
        const int g = g_lo + gi;
        const int* __restrict__ rowidx =
            indices + (size_t)g * NR1 * IDX_COLS + 3;   // wave-uniform
        float s0 = 0.f, s1 = 0.f;
        int cnt = 0;
#pragma unroll
        for (int c = 0; c < KCTX; ++c) {
          const int idx = rowidx[c];
          const unsigned w = *(const unsigned*)(P3b + (size_t)idx * H + jj);
          s0 += bf2f((unsigned short)(w & 0xffffu));
          s1 += bf2f((unsigned short)(w >> 16));
          cnt += (idx > 0) ? 1 : 0;
        }
        const float rn = 1.f / (float)((cnt > 1) ? cnt : 1);
        float2 o;
        o.x = b1v.x + s0 * rn;
        o.y = b1v.y + s1 * rn;
        *(float2*)&cgs[wv][gi][jj] = o;
      }
    }
  }
  __builtin_amdgcn_wave_barrier();   // scheduling fence (no-op instruction)

  // ---- phase 3: A-fragments (bf16) ----
  short8 A[2][4];
#pragma unroll
  for (int rt = 0; rt < 2; ++rt) {
#pragma unroll
    for (int kt = 0; kt < 4; ++kt) {
      union { short8 v; unsigned short s[8]; } va, vb;
      va.v = ua[rt][kt];
      vb.v = ub[rt][kt];
      const float4 c0 = *(const float4*)&cgs[wv][gl[rt]][kt * 32 + quad * 8];
      const float4 c1 = *(const float4*)&cgs[wv][gl[rt]][kt * 32 + quad * 8 + 4];
      const float h0 = fmaxf(bf2f(va.s[0]) + bf2f(vb.s[0]) + c0.x, 0.f);
      const float h1 = fmaxf(bf2f(va.s[1]) + bf2f(vb.s[1]) + c0.y, 0.f);
      const float h2 = fmaxf(bf2f(va.s[2]) + bf2f(vb.s[2]) + c0.z, 0.f);
      const float h3 = fmaxf(bf2f(va.s[3]) + bf2f(vb.s[3]) + c0.w, 0.f);
      const float h4 = fmaxf(bf2f(va.s[4]) + bf2f(vb.s[4]) + c1.x, 0.f);
      const float h5 = fmaxf(bf2f(va.s[5]) + bf2f(vb.s[5]) + c1.y, 0.f);
      const float h6 = fmaxf(bf2f(va.s[6]) + bf2f(vb.s[6]) + c1.z, 0.f);
      const float h7 = fmaxf(bf2f(va.s[7]) + bf2f(vb.s[7]) + c1.w, 0.f);
      union { short8 v; unsigned u[4]; } pk;
      pk.u[0] = pkbf(h0, h1);
      pk.u[1] = pkbf(h2, h3);
      pk.u[2] = pkbf(h4, h5);
      pk.u[3] = pkbf(h6, h7);
      A[rt][kt] = pk.v;
    }
  }

  // ---- phase 4: MFMA layer 2 (B from w2f, coalesced, L1-resident) ----
  f32x4 acc[2][4];
#pragma unroll
  for (int rt = 0; rt < 2; ++rt)
#pragma unroll
    for (int ct = 0; ct < 4; ++ct) acc[rt][ct] = (f32x4)(0.f);

#pragma unroll
  for (int kt = 0; kt < 4; ++kt) {
#pragma unroll
    for (int ct = 0; ct < 4; ++ct) {
      const short8 Bf = w2f[(kt * 4 + ct) * 64 + lane];
#pragma unroll
      for (int rt = 0; rt < 2; ++rt)
        acc[rt][ct] = __builtin_amdgcn_mfma_f32_16x16x32_bf16(
            A[rt][kt], Bf, acc[rt][ct], 0, 0, 0);
    }
  }

  // ---- epilogue: layer 3 + column reduction ----
  float b2v[4], w3v[4];
#pragma unroll
  for (int ct = 0; ct < 4; ++ct) {
    b2v[ct] = b2[ct * 16 + col];
    w3v[ct] = W3[ct * 16 + col];
  }
  const float bias3 = b3[0];
#pragma unroll
  for (int rt = 0; rt < 2; ++rt) {
#pragma unroll
    for (int reg = 0; reg < 4; ++reg) {
      float s = 0.f;
#pragma unroll
      for (int ct = 0; ct < 4; ++ct)
        s += fmaxf(acc[rt][ct][reg] + b2v[ct], 0.f) * w3v[ct];
      s += __shfl_xor(s, 1);
      s += __shfl_xor(s, 2);
      s += __shfl_xor(s, 4);
      s += __shfl_xor(s, 8);
      if (col == 0) {
        const int row = Rw + rt * 16 + quad * 4 + reg;   // C row = quad*4+reg
        if (row < N_ROWS) out[row] = s + bias3;
      }
    }
  }
}

// ---------------------------------------------------------------------------
extern "C" void kernel_launch(void* const* d_in, const int* in_sizes, int n_in,
                              void* d_out, int out_size, void* d_ws, size_t ws_size,
                              hipStream_t stream) {
  const int*   indices = (const int*)  d_in[0];
  // d_in[1] = nr (scalar, fixed at 24)
  const float* x  = (const float*)d_in[2];
  const float* W1 = (const float*)d_in[3];
  const float* b1 = (const float*)d_in[4];
  const float* W2 = (const float*)d_in[5];
  const float* b2 = (const float*)d_in[6];
  const float* W3 = (const float*)d_in[7];
  const float* b3 = (const float*)d_in[8];
  float* out = (float*)d_out;

  // Workspace: Pb (bf16 7.68 MB) | w2f (16 KB) | idx2 (4 MB)
  unsigned short* Pb  = (unsigned short*)d_ws;
  unsigned short* P1b = Pb;
  unsigned short* P2b = Pb + (size_t)NODES * H;
  unsigned short* P3b = Pb + (size_t)2 * NODES * H;
  short8* w2f = (short8*)(Pb + (size_t)3 * NODES * H);
  int2*   idx2 = (int2*)((char*)w2f + 1024 * sizeof(short8));

  k_pack<<<(N_ROWS + 255) / 256, 256, 0, stream>>>(indices, W2, idx2, w2f);
  dim3 gpre((NODES + PN - 1) / PN, 3);
  k_precompute<<<gpre, 256, 0, stream>>>(x, W1, Pb);
  k_main<<<(N_ROWS + RPB - 1) / RPB, 256, 0, stream>>>(idx2, indices,
                                                       P1b, P2b, P3b, w2f,
                                                       b1, b2, W3, b3, out);
}

// Round 10
// 166.801 us; speedup vs baseline: 1.4577x; 1.1846x over previous
//
#include <hip/hip_runtime.h>
#include <hip/hip_bf16.h>

// Problem constants (fixed by the reference setup)
#define N_ROWS   500000
#define NR1      25        // nr + 1
#define NGROUPS  20000     // N_ROWS / NR1
#define KCTX     20        // K context indices
#define H        128
#define NODES    10000
#define IDX_COLS 23        // 3 + K

#define RPB      128       // rows per k_main block

typedef __attribute__((ext_vector_type(8))) short short8;   // 8 bf16 = 4 VGPRs
typedef __attribute__((ext_vector_type(4))) float f32x4;    // MFMA C/D

// pack two floats -> two bf16 (RNE) as a 32-bit word
__device__ __forceinline__ unsigned pkbf(float lo, float hi) {
  __hip_bfloat162 h = __float22bfloat162_rn(make_float2(lo, hi));
  union { __hip_bfloat162 h; unsigned u; } c; c.h = h;
  return c.u;
}
__device__ __forceinline__ float bf2f(unsigned short u) {
  union { unsigned u; float f; } c; c.u = ((unsigned)u) << 16; return c.f;
}

// ---------------------------------------------------------------------------
// Kernel A (v5): fused precompute + index pack.
//  blockIdx.y = 0..2 : P[m] = x @ W1m.T via single-bf16 MFMA, P stored bf16
//                      (bf16 rounding verified harmless R4-R8: absmax 1.22e-4)
//  blockIdx.y = 3    : grid-stride (i0,i1) -> idx2 pack; runs CONCURRENTLY
//                      with the y=0..2 blocks (was a serial k_pack launch).
// ---------------------------------------------------------------------------
#define PN 64
#define PRE_BLOCKS ((NODES + PN - 1) / PN)   // 157
__global__ __launch_bounds__(256) void k_precompute(
    const float* __restrict__ x, const float* __restrict__ W1,
    const int* __restrict__ indices,
    unsigned short* __restrict__ Pb, int2* __restrict__ idx2) {
  const int tid = threadIdx.x;
  const int m   = blockIdx.y;

  if (m == 3) {
    // ---- index pack slice: 157 blocks, grid-stride over 500000 rows ----
    const int stride = PRE_BLOCKS * 256;
    for (int r = blockIdx.x * 256 + tid; r < N_ROWS; r += stride) {
      idx2[r] = make_int2(indices[(size_t)r * IDX_COLS + 0],
                          indices[(size_t)r * IDX_COLS + 1]);
    }
    return;
  }

  __shared__ short wlds[128][136];   // bf16 W1m[j][k], padded: 34.8 KB
  const int tbase = blockIdx.x * PN;       // node tile base

#pragma unroll
  for (int it = 0; it < 16; ++it) {
    const int f  = it * 256 + tid;         // 0..4095 float4s (128 j x 32)
    const int j  = f >> 5;
    const int q4 = f & 31;
    const float4 v = *(const float4*)(W1 + (size_t)j * (3 * H) + m * H + q4 * 4);
    *(unsigned*)&wlds[j][q4 * 4]     = pkbf(v.x, v.y);
    *(unsigned*)&wlds[j][q4 * 4 + 2] = pkbf(v.z, v.w);
  }
  __syncthreads();

  const int lane = tid & 63;
  const int wv   = tid >> 6;
  const int col  = lane & 15;
  const int quad = lane >> 4;

  int node = tbase + wv * 16 + col;
  if (node > NODES - 1) node = NODES - 1;
  const float4* __restrict__ xr = (const float4*)(x + (size_t)node * H);

  short8 Af[4];
#pragma unroll
  for (int kt = 0; kt < 4; ++kt) {
    const int f4 = kt * 8 + quad * 2;
    const float4 v0 = xr[f4], v1 = xr[f4 + 1];
    union { short8 v; unsigned u[4]; } pk;
    pk.u[0] = pkbf(v0.x, v0.y);
    pk.u[1] = pkbf(v0.z, v0.w);
    pk.u[2] = pkbf(v1.x, v1.y);
    pk.u[3] = pkbf(v1.z, v1.w);
    Af[kt] = pk.v;
  }

  f32x4 acc[8];
#pragma unroll
  for (int ct = 0; ct < 8; ++ct) acc[ct] = (f32x4)(0.f);

#pragma unroll
  for (int kt = 0; kt < 4; ++kt) {
#pragma unroll
    for (int ct = 0; ct < 8; ++ct) {
      const short8 Bf = *(const short8*)&wlds[ct * 16 + col][kt * 32 + quad * 8];
      acc[ct] = __builtin_amdgcn_mfma_f32_16x16x32_bf16(Af[kt], Bf, acc[ct], 0, 0, 0);
    }
  }

  unsigned short* __restrict__ Pm = Pb + (size_t)m * NODES * H;
#pragma unroll
  for (int reg = 0; reg < 4; ++reg) {
    const int n = tbase + wv * 16 + quad * 4 + reg;
    if (n < NODES) {
#pragma unroll
      for (int ct = 0; ct < 8; ++ct) {
        union { unsigned u; unsigned short s[2]; } c;
        c.u = pkbf(acc[ct][reg], 0.f);
        Pm[(size_t)n * H + ct * 16 + col] = c.s[0];
      }
    }
  }
}

// ---------------------------------------------------------------------------
// Kernel C (v9) == R4 structure (proven 78 us), ctx phase vectorized.
//  Phase 0a: W2 -> LDS bf16 (w2s[n][k] padded; broadcast B-frags).
//  Phase 0b: <=7 ctx-group rows -> cgs LDS, block-cooperative:
//            4 groups/iter, each thread reads u32 (2 cols) of P3.
//  ONE barrier. Gathers issued AFTER it (no vmcnt-drain amplification:
//  hoisting them above the barrier cost +70 us in R5/R6/R7).
//  Phase 1:  idx2 -> P1/P2 short8 gathers -> bf16 A-frags.
//  Phase 2:  16x16x32 bf16 MFMA layer 2;  epilogue: layer 3 + shfl reduce.
// Block = 256 threads (4 waves), 128 rows; wave w owns rows [w*32, +32).
// ---------------------------------------------------------------------------
__global__ __launch_bounds__(256) void k_main(
    const int* __restrict__ indices, const int2* __restrict__ idx2,
    const unsigned short* __restrict__ P1b, const unsigned short* __restrict__ P2b,
    const unsigned short* __restrict__ P3b,
    const float* __restrict__ W2, const float* __restrict__ b1,
    const float* __restrict__ b2, const float* __restrict__ W3,
    const float* __restrict__ b3, float* __restrict__ out) {
  __shared__ short w2s[64][136];   // bf16 W2[n][k], padded: 17.4 KB
  __shared__ float cgs[7][132];    // ctx rows (b1 folded), padded: 3.7 KB

  const int tid   = threadIdx.x;
  const int rbase = blockIdx.x * RPB;
  const int gbase = rbase / NR1;

  // ---- phase 0a: W2 -> LDS bf16 (coalesced float2 reads) ----
  for (int idx = tid; idx < 64 * 64; idx += 256) {
    const int n  = idx >> 6;        // row 0..63
    const int kp = idx & 63;        // k-pair 0..63
    const float2 w = *(const float2*)(W2 + (size_t)n * H + kp * 2);
    *(unsigned*)&w2s[n][kp * 2] = pkbf(w.x, w.y);
  }

  // ---- phase 0b: ctx groups, 4 per iteration, u32 (2-col) P3 reads ----
  {
    int rlast = rbase + RPB - 1; if (rlast > N_ROWS - 1) rlast = N_ROWS - 1;
    const int G   = rlast / NR1 - gbase + 1;   // <= 7
    const int jj  = (tid & 63) * 2;            // 2 cols per thread
    const int sub = tid >> 6;                  // group sub-slot 0..3
    const float2 b1v = *(const float2*)(b1 + jj);
#pragma unroll
    for (int it = 0; it < 2; ++it) {
      const int gi = it * 4 + sub;
      if (gi < G) {
        const int* __restrict__ rowidx =
            indices + (size_t)(gbase + gi) * NR1 * IDX_COLS + 3;  // wave-uniform
        float s0 = 0.f, s1 = 0.f;
        int cnt = 0;
#pragma unroll
        for (int c = 0; c < KCTX; ++c) {
          const int idx = rowidx[c];
          const unsigned w = *(const unsigned*)(P3b + (size_t)idx * H + jj);
          s0 += bf2f((unsigned short)(w & 0xffffu));
          s1 += bf2f((unsigned short)(w >> 16));
          cnt += (idx > 0) ? 1 : 0;
        }
        const float rn = 1.f / (float)((cnt > 1) ? cnt : 1);
        cgs[gi][jj]     = b1v.x + s0 * rn;
        cgs[gi][jj + 1] = b1v.y + s1 * rn;
      }
    }
  }
  __syncthreads();

  // ---- phase 1: idx2 -> gathers -> A-fragments ----
  const int lane = tid & 63;
  const int wv   = tid >> 6;
  const int col  = lane & 15;
  const int quad = lane >> 4;
  const int Rw   = rbase + wv * 32;

  int gl[2];
  short8 ua[2][4], ub[2][4];
#pragma unroll
  for (int rt = 0; rt < 2; ++rt) {
    const int r  = Rw + rt * 16 + col;
    const int rc = (r < N_ROWS) ? r : (N_ROWS - 1);
    const int2 ii = idx2[rc];
    const short8* __restrict__ pa = (const short8*)(P1b + (size_t)ii.x * H);
    const short8* __restrict__ pb = (const short8*)(P2b + (size_t)ii.y * H);
#pragma unroll
    for (int kt = 0; kt < 4; ++kt) {
      ua[rt][kt] = pa[kt * 4 + quad];
      ub[rt][kt] = pb[kt * 4 + quad];
    }
    gl[rt] = rc / NR1 - gbase;
  }

  short8 A[2][4];
#pragma unroll
  for (int rt = 0; rt < 2; ++rt) {
#pragma unroll
    for (int kt = 0; kt < 4; ++kt) {
      union { short8 v; unsigned short s[8]; } va, vb;
      va.v = ua[rt][kt];
      vb.v = ub[rt][kt];
      const float4 c0 = *(const float4*)&cgs[gl[rt]][kt * 32 + quad * 8];
      const float4 c1 = *(const float4*)&cgs[gl[rt]][kt * 32 + quad * 8 + 4];
      const float h0 = fmaxf(bf2f(va.s[0]) + bf2f(vb.s[0]) + c0.x, 0.f);
      const float h1 = fmaxf(bf2f(va.s[1]) + bf2f(vb.s[1]) + c0.y, 0.f);
      const float h2 = fmaxf(bf2f(va.s[2]) + bf2f(vb.s[2]) + c0.z, 0.f);
      const float h3 = fmaxf(bf2f(va.s[3]) + bf2f(vb.s[3]) + c0.w, 0.f);
      const float h4 = fmaxf(bf2f(va.s[4]) + bf2f(vb.s[4]) + c1.x, 0.f);
      const float h5 = fmaxf(bf2f(va.s[5]) + bf2f(vb.s[5]) + c1.y, 0.f);
      const float h6 = fmaxf(bf2f(va.s[6]) + bf2f(vb.s[6]) + c1.z, 0.f);
      const float h7 = fmaxf(bf2f(va.s[7]) + bf2f(vb.s[7]) + c1.w, 0.f);
      union { short8 v; unsigned u[4]; } pk;
      pk.u[0] = pkbf(h0, h1);
      pk.u[1] = pkbf(h2, h3);
      pk.u[2] = pkbf(h4, h5);
      pk.u[3] = pkbf(h6, h7);
      A[rt][kt] = pk.v;
    }
  }

  // ---- phase 2: MFMA layer 2 ----
  f32x4 acc[2][4];
#pragma unroll
  for (int rt = 0; rt < 2; ++rt)
#pragma unroll
    for (int ct = 0; ct < 4; ++ct) acc[rt][ct] = (f32x4)(0.f);

#pragma unroll
  for (int kt = 0; kt < 4; ++kt) {
#pragma unroll
    for (int ct = 0; ct < 4; ++ct) {
      const short8 Bf = *(const short8*)&w2s[ct * 16 + col][kt * 32 + quad * 8];
#pragma unroll
      for (int rt = 0; rt < 2; ++rt)
        acc[rt][ct] = __builtin_amdgcn_mfma_f32_16x16x32_bf16(
            A[rt][kt], Bf, acc[rt][ct], 0, 0, 0);
    }
  }

  // ---- epilogue: layer 3 + column reduction ----
  float b2v[4], w3v[4];
#pragma unroll
  for (int ct = 0; ct < 4; ++ct) {
    b2v[ct] = b2[ct * 16 + col];
    w3v[ct] = W3[ct * 16 + col];
  }
  const float bias3 = b3[0];
#pragma unroll
  for (int rt = 0; rt < 2; ++rt) {
#pragma unroll
    for (int reg = 0; reg < 4; ++reg) {
      float s = 0.f;
#pragma unroll
      for (int ct = 0; ct < 4; ++ct)
        s += fmaxf(acc[rt][ct][reg] + b2v[ct], 0.f) * w3v[ct];
      s += __shfl_xor(s, 1);
      s += __shfl_xor(s, 2);
      s += __shfl_xor(s, 4);
      s += __shfl_xor(s, 8);
      if (col == 0) {
        const int row = Rw + rt * 16 + quad * 4 + reg;   // C row = quad*4+reg
        if (row < N_ROWS) out[row] = s + bias3;
      }
    }
  }
}

// ---------------------------------------------------------------------------
extern "C" void kernel_launch(void* const* d_in, const int* in_sizes, int n_in,
                              void* d_out, int out_size, void* d_ws, size_t ws_size,
                              hipStream_t stream) {
  const int*   indices = (const int*)  d_in[0];
  // d_in[1] = nr (scalar, fixed at 24)
  const float* x  = (const float*)d_in[2];
  const float* W1 = (const float*)d_in[3];
  const float* b1 = (const float*)d_in[4];
  const float* W2 = (const float*)d_in[5];
  const float* b2 = (const float*)d_in[6];
  const float* W3 = (const float*)d_in[7];
  const float* b3 = (const float*)d_in[8];
  float* out = (float*)d_out;

  // Workspace: Pb (bf16 7.68 MB) | idx2 (4 MB)
  unsigned short* Pb  = (unsigned short*)d_ws;
  unsigned short* P1b = Pb;
  unsigned short* P2b = Pb + (size_t)NODES * H;
  unsigned short* P3b = Pb + (size_t)2 * NODES * H;
  int2* idx2 = (int2*)(Pb + (size_t)3 * NODES * H);

  dim3 gpre(PRE_BLOCKS, 4);   // y=0..2: P slices, y=3: idx pack (concurrent)
  k_precompute<<<gpre, 256, 0, stream>>>(x, W1, indices, Pb, idx2);
  k_main<<<(N_ROWS + RPB - 1) / RPB, 256, 0, stream>>>(indices, idx2,
                                                       P1b, P2b, P3b,
                                                       W2, b1, b2, W3, b3, out);
}

// Round 11
// 161.873 us; speedup vs baseline: 1.5021x; 1.0304x over previous
//
#include <hip/hip_runtime.h>
#include <hip/hip_bf16.h>

// Problem constants (fixed by the reference setup)
#define N_ROWS   500000
#define NR1      25        // nr + 1
#define NGROUPS  20000     // N_ROWS / NR1
#define KCTX     20        // K context indices
#define H        128
#define NODES    10000
#define IDX_COLS 23        // 3 + K

#define RPB      256       // rows per k_main block: TWO 128-row tiles

typedef __attribute__((ext_vector_type(8))) short short8;   // 8 bf16 = 4 VGPRs
typedef __attribute__((ext_vector_type(4))) float f32x4;    // MFMA C/D

// pack two floats -> two bf16 (RNE) as a 32-bit word
__device__ __forceinline__ unsigned pkbf(float lo, float hi) {
  __hip_bfloat162 h = __float22bfloat162_rn(make_float2(lo, hi));
  union { __hip_bfloat162 h; unsigned u; } c; c.h = h;
  return c.u;
}
__device__ __forceinline__ float bf2f(unsigned short u) {
  union { unsigned u; float f; } c; c.u = ((unsigned)u) << 16; return c.f;
}

// ---------------------------------------------------------------------------
// Kernel A (v5): fused precompute + index pack (unchanged from R9).
//  y = 0..2 : P[m] = x @ W1m.T via bf16 MFMA, P stored bf16
//  y = 3    : grid-stride (i0,i1) -> idx2 pack (concurrent with y=0..2)
// ---------------------------------------------------------------------------
#define PN 64
#define PRE_BLOCKS ((NODES + PN - 1) / PN)   // 157
__global__ __launch_bounds__(256) void k_precompute(
    const float* __restrict__ x, const float* __restrict__ W1,
    const int* __restrict__ indices,
    unsigned short* __restrict__ Pb, int2* __restrict__ idx2) {
  const int tid = threadIdx.x;
  const int m   = blockIdx.y;

  if (m == 3) {
    const int stride = PRE_BLOCKS * 256;
    for (int r = blockIdx.x * 256 + tid; r < N_ROWS; r += stride) {
      idx2[r] = make_int2(indices[(size_t)r * IDX_COLS + 0],
                          indices[(size_t)r * IDX_COLS + 1]);
    }
    return;
  }

  __shared__ short wlds[128][136];   // bf16 W1m[j][k], padded: 34.8 KB
  const int tbase = blockIdx.x * PN;

#pragma unroll
  for (int it = 0; it < 16; ++it) {
    const int f  = it * 256 + tid;
    const int j  = f >> 5;
    const int q4 = f & 31;
    const float4 v = *(const float4*)(W1 + (size_t)j * (3 * H) + m * H + q4 * 4);
    *(unsigned*)&wlds[j][q4 * 4]     = pkbf(v.x, v.y);
    *(unsigned*)&wlds[j][q4 * 4 + 2] = pkbf(v.z, v.w);
  }
  __syncthreads();

  const int lane = tid & 63;
  const int wv   = tid >> 6;
  const int col  = lane & 15;
  const int quad = lane >> 4;

  int node = tbase + wv * 16 + col;
  if (node > NODES - 1) node = NODES - 1;
  const float4* __restrict__ xr = (const float4*)(x + (size_t)node * H);

  short8 Af[4];
#pragma unroll
  for (int kt = 0; kt < 4; ++kt) {
    const int f4 = kt * 8 + quad * 2;
    const float4 v0 = xr[f4], v1 = xr[f4 + 1];
    union { short8 v; unsigned u[4]; } pk;
    pk.u[0] = pkbf(v0.x, v0.y);
    pk.u[1] = pkbf(v0.z, v0.w);
    pk.u[2] = pkbf(v1.x, v1.y);
    pk.u[3] = pkbf(v1.z, v1.w);
    Af[kt] = pk.v;
  }

  f32x4 acc[8];
#pragma unroll
  for (int ct = 0; ct < 8; ++ct) acc[ct] = (f32x4)(0.f);

#pragma unroll
  for (int kt = 0; kt < 4; ++kt) {
#pragma unroll
    for (int ct = 0; ct < 8; ++ct) {
      const short8 Bf = *(const short8*)&wlds[ct * 16 + col][kt * 32 + quad * 8];
      acc[ct] = __builtin_amdgcn_mfma_f32_16x16x32_bf16(Af[kt], Bf, acc[ct], 0, 0, 0);
    }
  }

  unsigned short* __restrict__ Pm = Pb + (size_t)m * NODES * H;
#pragma unroll
  for (int reg = 0; reg < 4; ++reg) {
    const int n = tbase + wv * 16 + quad * 4 + reg;
    if (n < NODES) {
#pragma unroll
      for (int ct = 0; ct < 8; ++ct) {
        union { unsigned u; unsigned short s[2]; } c;
        c.u = pkbf(acc[ct][reg], 0.f);
        Pm[(size_t)n * H + ct * 16 + col] = c.s[0];
      }
    }
  }
}

// ---------------------------------------------------------------------------
// Kernel C (v10): two-tile software-pipelined main kernel.
//  Per block (256 rows = 2 tiles of 128):
//   Phase 0a: W2 -> LDS bf16 (once, amortized over 2 tiles)
//   Phase 0b: <=12 ctx-group rows -> cgs (block-cooperative, u32 P3 reads)
//   ONE barrier (nothing held across it — R5-R7: hoisting cost +70us)
//   Tile pipeline: gathers0 -> A0 -> ISSUE gathers1 -> MFMA0+epi0+store0
//                  -> A1 (latency hidden behind tile-0 compute) -> MFMA1+epi1
// Block = 256 threads (4 waves); wave w owns rows [t*128 + w*32, +32).
// ---------------------------------------------------------------------------
__global__ __launch_bounds__(256) void k_main(
    const int* __restrict__ indices, const int2* __restrict__ idx2,
    const unsigned short* __restrict__ P1b, const unsigned short* __restrict__ P2b,
    const unsigned short* __restrict__ P3b,
    const float* __restrict__ W2, const float* __restrict__ b1,
    const float* __restrict__ b2, const float* __restrict__ W3,
    const float* __restrict__ b3, float* __restrict__ out) {
  __shared__ short w2s[64][136];   // bf16 W2[n][k], padded: 17.4 KB
  __shared__ float cgs[12][132];   // ctx rows (b1 folded), padded: 6.3 KB

  const int tid   = threadIdx.x;
  const int rbase = blockIdx.x * RPB;
  const int gbase = rbase / NR1;

  // ---- phase 0a: W2 -> LDS bf16 (coalesced float2 reads) ----
  for (int idx = tid; idx < 64 * 64; idx += 256) {
    const int n  = idx >> 6;
    const int kp = idx & 63;
    const float2 w = *(const float2*)(W2 + (size_t)n * H + kp * 2);
    *(unsigned*)&w2s[n][kp * 2] = pkbf(w.x, w.y);
  }

  // ---- phase 0b: ctx groups (<=12), 4 per iteration, u32 P3 reads ----
  {
    int rlast = rbase + RPB - 1; if (rlast > N_ROWS - 1) rlast = N_ROWS - 1;
    const int G   = rlast / NR1 - gbase + 1;   // <= 12
    const int jj  = (tid & 63) * 2;
    const int sub = tid >> 6;
    const float2 b1v = *(const float2*)(b1 + jj);
#pragma unroll
    for (int it = 0; it < 3; ++it) {
      const int gi = it * 4 + sub;
      if (gi < G) {
        const int* __restrict__ rowidx =
            indices + (size_t)(gbase + gi) * NR1 * IDX_COLS + 3;  // wave-uniform
        float s0 = 0.f, s1 = 0.f;
        int cnt = 0;
#pragma unroll
        for (int c = 0; c < KCTX; ++c) {
          const int idx = rowidx[c];
          const unsigned w = *(const unsigned*)(P3b + (size_t)idx * H + jj);
          s0 += bf2f((unsigned short)(w & 0xffffu));
          s1 += bf2f((unsigned short)(w >> 16));
          cnt += (idx > 0) ? 1 : 0;
        }
        const float rn = 1.f / (float)((cnt > 1) ? cnt : 1);
        cgs[gi][jj]     = b1v.x + s0 * rn;
        cgs[gi][jj + 1] = b1v.y + s1 * rn;
      }
    }
  }
  __syncthreads();

  const int lane = tid & 63;
  const int wv   = tid >> 6;
  const int col  = lane & 15;
  const int quad = lane >> 4;
  const int R0   = rbase + wv * 32;          // tile-0 wave base
  const int R1   = rbase + 128 + wv * 32;    // tile-1 wave base

  // epilogue constants (L1-hot, load once)
  float b2v[4], w3v[4];
#pragma unroll
  for (int ct = 0; ct < 4; ++ct) {
    b2v[ct] = b2[ct * 16 + col];
    w3v[ct] = W3[ct * 16 + col];
  }
  const float bias3 = b3[0];

  // ---- tile 0: gathers ----
  int gl0[2];
  short8 ua0[2][4], ub0[2][4];
#pragma unroll
  for (int rt = 0; rt < 2; ++rt) {
    const int r  = R0 + rt * 16 + col;
    const int rc = (r < N_ROWS) ? r : (N_ROWS - 1);
    const int2 ii = idx2[rc];
    const short8* __restrict__ pa = (const short8*)(P1b + (size_t)ii.x * H);
    const short8* __restrict__ pb = (const short8*)(P2b + (size_t)ii.y * H);
#pragma unroll
    for (int kt = 0; kt < 4; ++kt) {
      ua0[rt][kt] = pa[kt * 4 + quad];
      ub0[rt][kt] = pb[kt * 4 + quad];
    }
    gl0[rt] = rc / NR1 - gbase;
  }

  // ---- tile 0: A-fragments (waits on tile-0 gathers only) ----
  short8 A0[2][4];
#pragma unroll
  for (int rt = 0; rt < 2; ++rt) {
#pragma unroll
    for (int kt = 0; kt < 4; ++kt) {
      union { short8 v; unsigned short s[8]; } va, vb;
      va.v = ua0[rt][kt];
      vb.v = ub0[rt][kt];
      const float4 c0 = *(const float4*)&cgs[gl0[rt]][kt * 32 + quad * 8];
      const float4 c1 = *(const float4*)&cgs[gl0[rt]][kt * 32 + quad * 8 + 4];
      const float h0 = fmaxf(bf2f(va.s[0]) + bf2f(vb.s[0]) + c0.x, 0.f);
      const float h1 = fmaxf(bf2f(va.s[1]) + bf2f(vb.s[1]) + c0.y, 0.f);
      const float h2 = fmaxf(bf2f(va.s[2]) + bf2f(vb.s[2]) + c0.z, 0.f);
      const float h3 = fmaxf(bf2f(va.s[3]) + bf2f(vb.s[3]) + c0.w, 0.f);
      const float h4 = fmaxf(bf2f(va.s[4]) + bf2f(vb.s[4]) + c1.x, 0.f);
      const float h5 = fmaxf(bf2f(va.s[5]) + bf2f(vb.s[5]) + c1.y, 0.f);
      const float h6 = fmaxf(bf2f(va.s[6]) + bf2f(vb.s[6]) + c1.z, 0.f);
      const float h7 = fmaxf(bf2f(va.s[7]) + bf2f(vb.s[7]) + c1.w, 0.f);
      union { short8 v; unsigned u[4]; } pk;
      pk.u[0] = pkbf(h0, h1);
      pk.u[1] = pkbf(h2, h3);
      pk.u[2] = pkbf(h4, h5);
      pk.u[3] = pkbf(h6, h7);
      A0[rt][kt] = pk.v;
    }
  }

  // ---- tile 1: ISSUE gathers now (latency overlaps tile-0 MFMA/epilogue) ----
  int gl1[2];
  short8 ua1[2][4], ub1[2][4];
#pragma unroll
  for (int rt = 0; rt < 2; ++rt) {
    const int r  = R1 + rt * 16 + col;
    const int rc = (r < N_ROWS) ? r : (N_ROWS - 1);
    const int2 ii = idx2[rc];
    const short8* __restrict__ pa = (const short8*)(P1b + (size_t)ii.x * H);
    const short8* __restrict__ pb = (const short8*)(P2b + (size_t)ii.y * H);
#pragma unroll
    for (int kt = 0; kt < 4; ++kt) {
      ua1[rt][kt] = pa[kt * 4 + quad];
      ub1[rt][kt] = pb[kt * 4 + quad];
    }
    gl1[rt] = rc / NR1 - gbase;
  }

  // ---- tile 0: MFMA + epilogue + store ----
  {
    f32x4 acc[2][4];
#pragma unroll
    for (int rt = 0; rt < 2; ++rt)
#pragma unroll
      for (int ct = 0; ct < 4; ++ct) acc[rt][ct] = (f32x4)(0.f);
#pragma unroll
    for (int kt = 0; kt < 4; ++kt) {
#pragma unroll
      for (int ct = 0; ct < 4; ++ct) {
        const short8 Bf = *(const short8*)&w2s[ct * 16 + col][kt * 32 + quad * 8];
#pragma unroll
        for (int rt = 0; rt < 2; ++rt)
          acc[rt][ct] = __builtin_amdgcn_mfma_f32_16x16x32_bf16(
              A0[rt][kt], Bf, acc[rt][ct], 0, 0, 0);
      }
    }
#pragma unroll
    for (int rt = 0; rt < 2; ++rt) {
#pragma unroll
      for (int reg = 0; reg < 4; ++reg) {
        float s = 0.f;
#pragma unroll
        for (int ct = 0; ct < 4; ++ct)
          s += fmaxf(acc[rt][ct][reg] + b2v[ct], 0.f) * w3v[ct];
        s += __shfl_xor(s, 1);
        s += __shfl_xor(s, 2);
        s += __shfl_xor(s, 4);
        s += __shfl_xor(s, 8);
        if (col == 0) {
          const int row = R0 + rt * 16 + quad * 4 + reg;
          if (row < N_ROWS) out[row] = s + bias3;
        }
      }
    }
  }

  // ---- tile 1: A-fragments (gathers have been in flight through tile 0) ----
  short8 A1[2][4];
#pragma unroll
  for (int rt = 0; rt < 2; ++rt) {
#pragma unroll
    for (int kt = 0; kt < 4; ++kt) {
      union { short8 v; unsigned short s[8]; } va, vb;
      va.v = ua1[rt][kt];
      vb.v = ub1[rt][kt];
      const float4 c0 = *(const float4*)&cgs[gl1[rt]][kt * 32 + quad * 8];
      const float4 c1 = *(const float4*)&cgs[gl1[rt]][kt * 32 + quad * 8 + 4];
      const float h0 = fmaxf(bf2f(va.s[0]) + bf2f(vb.s[0]) + c0.x, 0.f);
      const float h1 = fmaxf(bf2f(va.s[1]) + bf2f(vb.s[1]) + c0.y, 0.f);
      const float h2 = fmaxf(bf2f(va.s[2]) + bf2f(vb.s[2]) + c0.z, 0.f);
      const float h3 = fmaxf(bf2f(va.s[3]) + bf2f(vb.s[3]) + c0.w, 0.f);
      const float h4 = fmaxf(bf2f(va.s[4]) + bf2f(vb.s[4]) + c1.x, 0.f);
      const float h5 = fmaxf(bf2f(va.s[5]) + bf2f(vb.s[5]) + c1.y, 0.f);
      const float h6 = fmaxf(bf2f(va.s[6]) + bf2f(vb.s[6]) + c1.z, 0.f);
      const float h7 = fmaxf(bf2f(va.s[7]) + bf2f(vb.s[7]) + c1.w, 0.f);
      union { short8 v; unsigned u[4]; } pk;
      pk.u[0] = pkbf(h0, h1);
      pk.u[1] = pkbf(h2, h3);
      pk.u[2] = pkbf(h4, h5);
      pk.u[3] = pkbf(h6, h7);
      A1[rt][kt] = pk.v;
    }
  }

  // ---- tile 1: MFMA + epilogue + store ----
  {
    f32x4 acc[2][4];
#pragma unroll
    for (int rt = 0; rt < 2; ++rt)
#pragma unroll
      for (int ct = 0; ct < 4; ++ct) acc[rt][ct] = (f32x4)(0.f);
#pragma unroll
    for (int kt = 0; kt < 4; ++kt) {
#pragma unroll
      for (int ct = 0; ct < 4; ++ct) {
        const short8 Bf = *(const short8*)&w2s[ct * 16 + col][kt * 32 + quad * 8];
#pragma unroll
        for (int rt = 0; rt < 2; ++rt)
          acc[rt][ct] = __builtin_amdgcn_mfma_f32_16x16x32_bf16(
              A1[rt][kt], Bf, acc[rt][ct], 0, 0, 0);
      }
    }
#pragma unroll
    for (int rt = 0; rt < 2; ++rt) {
#pragma unroll
      for (int reg = 0; reg < 4; ++reg) {
        float s = 0.f;
#pragma unroll
        for (int ct = 0; ct < 4; ++ct)
          s += fmaxf(acc[rt][ct][reg] + b2v[ct], 0.f) * w3v[ct];
        s += __shfl_xor(s, 1);
        s += __shfl_xor(s, 2);
        s += __shfl_xor(s, 4);
        s += __shfl_xor(s, 8);
        if (col == 0) {
          const int row = R1 + rt * 16 + quad * 4 + reg;
          if (row < N_ROWS) out[row] = s + bias3;
        }
      }
    }
  }
}

// ---------------------------------------------------------------------------
extern "C" void kernel_launch(void* const* d_in, const int* in_sizes, int n_in,
                              void* d_out, int out_size, void* d_ws, size_t ws_size,
                              hipStream_t stream) {
  const int*   indices = (const int*)  d_in[0];
  // d_in[1] = nr (scalar, fixed at 24)
  const float* x  = (const float*)d_in[2];
  const float* W1 = (const float*)d_in[3];
  const float* b1 = (const float*)d_in[4];
  const float* W2 = (const float*)d_in[5];
  const float* b2 = (const float*)d_in[6];
  const float* W3 = (const float*)d_in[7];
  const float* b3 = (const float*)d_in[8];
  float* out = (float*)d_out;

  // Workspace: Pb (bf16 7.68 MB) | idx2 (4 MB)
  unsigned short* Pb  = (unsigned short*)d_ws;
  unsigned short* P1b = Pb;
  unsigned short* P2b = Pb + (size_t)NODES * H;
  unsigned short* P3b = Pb + (size_t)2 * NODES * H;
  int2* idx2 = (int2*)(Pb + (size_t)3 * NODES * H);

  dim3 gpre(PRE_BLOCKS, 4);   // y=0..2: P slices, y=3: idx pack (concurrent)
  k_precompute<<<gpre, 256, 0, stream>>>(x, W1, indices, Pb, idx2);
  k_main<<<(N_ROWS + RPB - 1) / RPB, 256, 0, stream>>>(indices, idx2,
                                                       P1b, P2b, P3b,
                                                       W2, b1, b2, W3, b3, out);
}

// Round 12
// 158.036 us; speedup vs baseline: 1.5385x; 1.0243x over previous
//
#include <hip/hip_runtime.h>
#include <hip/hip_bf16.h>

// Problem constants (fixed by the reference setup)
#define N_ROWS   500000
#define NR1      25        // nr + 1
#define NGROUPS  20000     // N_ROWS / NR1
#define KCTX     20        // K context indices
#define H        128
#define NODES    10000
#define IDX_COLS 23        // 3 + K

#define NT       4         // tiles per block
#define RPB      (NT * 128)  // 512 rows per k_main block
#define MAXG     22        // max ctx groups spanned by 512 rows

typedef __attribute__((ext_vector_type(8))) short short8;   // 8 bf16 = 4 VGPRs
typedef __attribute__((ext_vector_type(4))) float f32x4;    // MFMA C/D

// pack two floats -> two bf16 (RNE) as a 32-bit word
__device__ __forceinline__ unsigned pkbf(float lo, float hi) {
  __hip_bfloat162 h = __float22bfloat162_rn(make_float2(lo, hi));
  union { __hip_bfloat162 h; unsigned u; } c; c.h = h;
  return c.u;
}
__device__ __forceinline__ float bf2f(unsigned short u) {
  union { unsigned u; float f; } c; c.u = ((unsigned)u) << 16; return c.f;
}

// ---------------------------------------------------------------------------
// Kernel A (v5): fused precompute + index pack (unchanged from R9/R10).
//  y = 0..2 : P[m] = x @ W1m.T via bf16 MFMA, P stored bf16
//  y = 3    : grid-stride (i0,i1) -> idx2 pack (concurrent with y=0..2)
// ---------------------------------------------------------------------------
#define PN 64
#define PRE_BLOCKS ((NODES + PN - 1) / PN)   // 157
__global__ __launch_bounds__(256) void k_precompute(
    const float* __restrict__ x, const float* __restrict__ W1,
    const int* __restrict__ indices,
    unsigned short* __restrict__ Pb, int2* __restrict__ idx2) {
  const int tid = threadIdx.x;
  const int m   = blockIdx.y;

  if (m == 3) {
    const int stride = PRE_BLOCKS * 256;
    for (int r = blockIdx.x * 256 + tid; r < N_ROWS; r += stride) {
      idx2[r] = make_int2(indices[(size_t)r * IDX_COLS + 0],
                          indices[(size_t)r * IDX_COLS + 1]);
    }
    return;
  }

  __shared__ short wlds[128][136];   // bf16 W1m[j][k], padded: 34.8 KB
  const int tbase = blockIdx.x * PN;

#pragma unroll
  for (int it = 0; it < 16; ++it) {
    const int f  = it * 256 + tid;
    const int j  = f >> 5;
    const int q4 = f & 31;
    const float4 v = *(const float4*)(W1 + (size_t)j * (3 * H) + m * H + q4 * 4);
    *(unsigned*)&wlds[j][q4 * 4]     = pkbf(v.x, v.y);
    *(unsigned*)&wlds[j][q4 * 4 + 2] = pkbf(v.z, v.w);
  }
  __syncthreads();

  const int lane = tid & 63;
  const int wv   = tid >> 6;
  const int col  = lane & 15;
  const int quad = lane >> 4;

  int node = tbase + wv * 16 + col;
  if (node > NODES - 1) node = NODES - 1;
  const float4* __restrict__ xr = (const float4*)(x + (size_t)node * H);

  short8 Af[4];
#pragma unroll
  for (int kt = 0; kt < 4; ++kt) {
    const int f4 = kt * 8 + quad * 2;
    const float4 v0 = xr[f4], v1 = xr[f4 + 1];
    union { short8 v; unsigned u[4]; } pk;
    pk.u[0] = pkbf(v0.x, v0.y);
    pk.u[1] = pkbf(v0.z, v0.w);
    pk.u[2] = pkbf(v1.x, v1.y);
    pk.u[3] = pkbf(v1.z, v1.w);
    Af[kt] = pk.v;
  }

  f32x4 acc[8];
#pragma unroll
  for (int ct = 0; ct < 8; ++ct) acc[ct] = (f32x4)(0.f);

#pragma unroll
  for (int kt = 0; kt < 4; ++kt) {
#pragma unroll
    for (int ct = 0; ct < 8; ++ct) {
      const short8 Bf = *(const short8*)&wlds[ct * 16 + col][kt * 32 + quad * 8];
      acc[ct] = __builtin_amdgcn_mfma_f32_16x16x32_bf16(Af[kt], Bf, acc[ct], 0, 0, 0);
    }
  }

  unsigned short* __restrict__ Pm = Pb + (size_t)m * NODES * H;
#pragma unroll
  for (int reg = 0; reg < 4; ++reg) {
    const int n = tbase + wv * 16 + quad * 4 + reg;
    if (n < NODES) {
#pragma unroll
      for (int ct = 0; ct < 8; ++ct) {
        union { unsigned u; unsigned short s[2]; } c;
        c.u = pkbf(acc[ct][reg], 0.f);
        Pm[(size_t)n * H + ct * 16 + col] = c.s[0];
      }
    }
  }
}

// ---------------------------------------------------------------------------
// Kernel C (v11): FOUR-tile software-pipelined main kernel (512 rows/block).
//  Phase 0a: W2 -> LDS bf16 (once per 512 rows)
//  Phase 0b: <=22 ctx-group rows -> cgs (block-cooperative, u32 P3 reads)
//  ONE barrier (R5-R7: holding gathers across it cost +70us)
//  Pipeline: g0 | A0 g1 C0 | A1 g2 C1 | A2 g3 C2 | A3 C3
//  (ping-pong gather buffers; per-stage live set identical to R10's 76-VGPR
//   pattern, so occupancy should hold)
// ---------------------------------------------------------------------------
__global__ __launch_bounds__(256) void k_main(
    const int* __restrict__ indices, const int2* __restrict__ idx2,
    const unsigned short* __restrict__ P1b, const unsigned short* __restrict__ P2b,
    const unsigned short* __restrict__ P3b,
    const float* __restrict__ W2, const float* __restrict__ b1,
    const float* __restrict__ b2, const float* __restrict__ W3,
    const float* __restrict__ b3, float* __restrict__ out) {
  __shared__ short w2s[64][136];      // bf16 W2[n][k], padded: 17.4 KB
  __shared__ float cgs[MAXG][132];    // ctx rows (b1 folded), padded: 11.6 KB

  const int tid   = threadIdx.x;
  const int rbase = blockIdx.x * RPB;
  const int gbase = rbase / NR1;

  // ---- phase 0a: W2 -> LDS bf16 (coalesced float2 reads) ----
  for (int idx = tid; idx < 64 * 64; idx += 256) {
    const int n  = idx >> 6;
    const int kp = idx & 63;
    const float2 w = *(const float2*)(W2 + (size_t)n * H + kp * 2);
    *(unsigned*)&w2s[n][kp * 2] = pkbf(w.x, w.y);
  }

  // ---- phase 0b: ctx groups (<=22), 4 per iteration, u32 P3 reads ----
  {
    int rlast = rbase + RPB - 1; if (rlast > N_ROWS - 1) rlast = N_ROWS - 1;
    const int G   = rlast / NR1 - gbase + 1;   // <= 22
    const int jj  = (tid & 63) * 2;
    const int sub = tid >> 6;
    const float2 b1v = *(const float2*)(b1 + jj);
#pragma unroll
    for (int it = 0; it < 6; ++it) {
      const int gi = it * 4 + sub;
      if (gi < G) {
        const int* __restrict__ rowidx =
            indices + (size_t)(gbase + gi) * NR1 * IDX_COLS + 3;  // wave-uniform
        float s0 = 0.f, s1 = 0.f;
        int cnt = 0;
#pragma unroll
        for (int c = 0; c < KCTX; ++c) {
          const int idx = rowidx[c];
          const unsigned w = *(const unsigned*)(P3b + (size_t)idx * H + jj);
          s0 += bf2f((unsigned short)(w & 0xffffu));
          s1 += bf2f((unsigned short)(w >> 16));
          cnt += (idx > 0) ? 1 : 0;
        }
        const float rn = 1.f / (float)((cnt > 1) ? cnt : 1);
        cgs[gi][jj]     = b1v.x + s0 * rn;
        cgs[gi][jj + 1] = b1v.y + s1 * rn;
      }
    }
  }
  __syncthreads();

  const int lane = tid & 63;
  const int wv   = tid >> 6;
  const int col  = lane & 15;
  const int quad = lane >> 4;

  // epilogue constants (L1-hot, load once)
  float b2v[4], w3v[4];
#pragma unroll
  for (int ct = 0; ct < 4; ++ct) {
    b2v[ct] = b2[ct * 16 + col];
    w3v[ct] = W3[ct * 16 + col];
  }
  const float bias3 = b3[0];

  // ping-pong gather buffers
  short8 ua[2][2][4], ub[2][2][4];
  int    gl[2][2];

  // issue tile-0 gathers
  {
    const int R = rbase + wv * 32;
#pragma unroll
    for (int rt = 0; rt < 2; ++rt) {
      const int r  = R + rt * 16 + col;
      const int rc = (r < N_ROWS) ? r : (N_ROWS - 1);
      const int2 ii = idx2[rc];
      const short8* __restrict__ pa = (const short8*)(P1b + (size_t)ii.x * H);
      const short8* __restrict__ pb = (const short8*)(P2b + (size_t)ii.y * H);
#pragma unroll
      for (int kt = 0; kt < 4; ++kt) {
        ua[0][rt][kt] = pa[kt * 4 + quad];
        ub[0][rt][kt] = pb[kt * 4 + quad];
      }
      gl[0][rt] = rc / NR1 - gbase;
    }
  }

#pragma unroll
  for (int t = 0; t < NT; ++t) {
    const int cur = t & 1;
    const int nxt = cur ^ 1;
    const int Rt  = rbase + t * 128 + wv * 32;

    // ---- build A-fragments for tile t (waits on its gathers only) ----
    short8 A[2][4];
#pragma unroll
    for (int rt = 0; rt < 2; ++rt) {
#pragma unroll
      for (int kt = 0; kt < 4; ++kt) {
        union { short8 v; unsigned short s[8]; } va, vb;
        va.v = ua[cur][rt][kt];
        vb.v = ub[cur][rt][kt];
        const float4 c0 = *(const float4*)&cgs[gl[cur][rt]][kt * 32 + quad * 8];
        const float4 c1 = *(const float4*)&cgs[gl[cur][rt]][kt * 32 + quad * 8 + 4];
        const float h0 = fmaxf(bf2f(va.s[0]) + bf2f(vb.s[0]) + c0.x, 0.f);
        const float h1 = fmaxf(bf2f(va.s[1]) + bf2f(vb.s[1]) + c0.y, 0.f);
        const float h2 = fmaxf(bf2f(va.s[2]) + bf2f(vb.s[2]) + c0.z, 0.f);
        const float h3 = fmaxf(bf2f(va.s[3]) + bf2f(vb.s[3]) + c0.w, 0.f);
        const float h4 = fmaxf(bf2f(va.s[4]) + bf2f(vb.s[4]) + c1.x, 0.f);
        const float h5 = fmaxf(bf2f(va.s[5]) + bf2f(vb.s[5]) + c1.y, 0.f);
        const float h6 = fmaxf(bf2f(va.s[6]) + bf2f(vb.s[6]) + c1.z, 0.f);
        const float h7 = fmaxf(bf2f(va.s[7]) + bf2f(vb.s[7]) + c1.w, 0.f);
        union { short8 v; unsigned u[4]; } pk;
        pk.u[0] = pkbf(h0, h1);
        pk.u[1] = pkbf(h2, h3);
        pk.u[2] = pkbf(h4, h5);
        pk.u[3] = pkbf(h6, h7);
        A[rt][kt] = pk.v;
      }
    }

    // ---- issue tile t+1 gathers (latency hides behind tile-t MFMA) ----
    if (t + 1 < NT) {
      const int Rn = rbase + (t + 1) * 128 + wv * 32;
#pragma unroll
      for (int rt = 0; rt < 2; ++rt) {
        const int r  = Rn + rt * 16 + col;
        const int rc = (r < N_ROWS) ? r : (N_ROWS - 1);
        const int2 ii = idx2[rc];
        const short8* __restrict__ pa = (const short8*)(P1b + (size_t)ii.x * H);
        const short8* __restrict__ pb = (const short8*)(P2b + (size_t)ii.y * H);
#pragma unroll
        for (int kt = 0; kt < 4; ++kt) {
          ua[nxt][rt][kt] = pa[kt * 4 + quad];
          ub[nxt][rt][kt] = pb[kt * 4 + quad];
        }
        gl[nxt][rt] = rc / NR1 - gbase;
      }
    }

    // ---- MFMA layer 2 + epilogue + store for tile t ----
    f32x4 acc[2][4];
#pragma unroll
    for (int rt = 0; rt < 2; ++rt)
#pragma unroll
      for (int ct = 0; ct < 4; ++ct) acc[rt][ct] = (f32x4)(0.f);
#pragma unroll
    for (int kt = 0; kt < 4; ++kt) {
#pragma unroll
      for (int ct = 0; ct < 4; ++ct) {
        const short8 Bf = *(const short8*)&w2s[ct * 16 + col][kt * 32 + quad * 8];
#pragma unroll
        for (int rt = 0; rt < 2; ++rt)
          acc[rt][ct] = __builtin_amdgcn_mfma_f32_16x16x32_bf16(
              A[rt][kt], Bf, acc[rt][ct], 0, 0, 0);
      }
    }
#pragma unroll
    for (int rt = 0; rt < 2; ++rt) {
#pragma unroll
      for (int reg = 0; reg < 4; ++reg) {
        float s = 0.f;
#pragma unroll
        for (int ct = 0; ct < 4; ++ct)
          s += fmaxf(acc[rt][ct][reg] + b2v[ct], 0.f) * w3v[ct];
        s += __shfl_xor(s, 1);
        s += __shfl_xor(s, 2);
        s += __shfl_xor(s, 4);
        s += __shfl_xor(s, 8);
        if (col == 0) {
          const int row = Rt + rt * 16 + quad * 4 + reg;   // C row = quad*4+reg
          if (row < N_ROWS) out[row] = s + bias3;
        }
      }
    }
  }
}

// ---------------------------------------------------------------------------
extern "C" void kernel_launch(void* const* d_in, const int* in_sizes, int n_in,
                              void* d_out, int out_size, void* d_ws, size_t ws_size,
                              hipStream_t stream) {
  const int*   indices = (const int*)  d_in[0];
  // d_in[1] = nr (scalar, fixed at 24)
  const float* x  = (const float*)d_in[2];
  const float* W1 = (const float*)d_in[3];
  const float* b1 = (const float*)d_in[4];
  const float* W2 = (const float*)d_in[5];
  const float* b2 = (const float*)d_in[6];
  const float* W3 = (const float*)d_in[7];
  const float* b3 = (const float*)d_in[8];
  float* out = (float*)d_out;

  // Workspace: Pb (bf16 7.68 MB) | idx2 (4 MB)
  unsigned short* Pb  = (unsigned short*)d_ws;
  unsigned short* P1b = Pb;
  unsigned short* P2b = Pb + (size_t)NODES * H;
  unsigned short* P3b = Pb + (size_t)2 * NODES * H;
  int2* idx2 = (int2*)(Pb + (size_t)3 * NODES * H);

  dim3 gpre(PRE_BLOCKS, 4);   // y=0..2: P slices, y=3: idx pack (concurrent)
  k_precompute<<<gpre, 256, 0, stream>>>(x, W1, indices, Pb, idx2);
  k_main<<<(N_ROWS + RPB - 1) / RPB, 256, 0, stream>>>(indices, idx2,
                                                       P1b, P2b, P3b,
                                                       W2, b1, b2, W3, b3, out);
}